// Round 9
// baseline (1535.146 us; speedup 1.0000x reference)
//
#include <hip/hip_runtime.h>

#define BB 256
#define TT 100
#define HH 512
#define G4 2048
#define INL 176
#define KIN 192
#define NCAT 16
#define NCONT 48
#define VV 32
#define EE 8
#define MTOT (BB*TT)
#define GRPB 32   // j-blocks per m-group
#define FS 16     // flag stride in ints (64B)

typedef unsigned short u16;
typedef unsigned int   u32;
typedef unsigned long long u64;
typedef __attribute__((ext_vector_type(8))) short bf16x8;
typedef __attribute__((ext_vector_type(4))) float f32x4;

__device__ __forceinline__ float bf2f(u16 u){
    union { u32 i; float f; } v; v.i = ((u32)u) << 16; return v.f;
}
__device__ __forceinline__ u16 f2bf(float f){
    union { float f; u32 i; } v; v.f = f;
    u32 b = v.i;
    b += 0x7FFFu + ((b >> 16) & 1u);   // round-to-nearest-even
    return (u16)(b >> 16);
}
// exact identity tanh(x) = 1 - 2/(e^{2x}+1); __expf precision << bf16 rounding
__device__ __forceinline__ float fast_tanh(float x){
    float e = __expf(2.f * x);
    return 1.f - 2.f / (e + 1.f);
}
// packed relu on 4 bf16 halves: zero any half with sign bit set (exact)
__device__ __forceinline__ u64 relu4_bf16(u64 v){
    u64 s = v & 0x8000800080008000ULL;
    u64 m = s - (s >> 15);            // 0x7FFF per negative half (no cross-half borrow)
    return v & ~(s | m);
}

// ---- canonical-name kernel: W_in fp32 [176][512] -> bf16 WinT [512][192] (pad) ----
__global__ void PredictionModel_58841051955204_kernel(
    const float* __restrict__ Win, u16* __restrict__ WinT){
    int idx = blockIdx.x*256 + threadIdx.x;
    if (idx >= HH*KIN) return;
    int h = idx / KIN, i = idx % KIN;
    WinT[idx] = (i < INL) ? f2bf(Win[i*HH + h]) : (u16)0;
}

// ---- bulk fp32 -> bf16 convert (weights) ----
__global__ void k_cvt(const float* __restrict__ in, u16* __restrict__ out, int n){
    int i = blockIdx.x*256 + threadIdx.x;
    if (i < n) out[i] = f2bf(in[i]);
}

// ---- featurize: fp32 inputs -> bf16 feat [25600][192] ----
__global__ void k_feat(const float* __restrict__ x, const float* __restrict__ mean,
                       const float* __restrict__ scale, const float* __restrict__ emb,
                       u16* __restrict__ feat){
    int idx = blockIdx.x*256 + threadIdx.x;
    int bt = idx >> 4, g = idx & 15;
    if (bt >= MTOT) return;
    const float* xr = x + (size_t)bt*64;
    u16* fr = feat + (size_t)bt*KIN;
    int k0 = g*4;
    int ci = (int)xr[k0];
    if (ci < 0) ci = 0;
    if (ci > VV-1) ci = VV-1;
    const float* ep = emb + (size_t)(g*VV + ci)*EE;
    int c0 = g*11;
    for (int e = 0; e < 8; e++) fr[c0+e] = f2bf(ep[e]);
    for (int j = 1; j <= 3; j++){
        int k = k0 + j;
        fr[c0 + 8 + (j-1)] = f2bf((xr[k] - mean[k]) / scale[k]);
    }
    fr[INL + g] = 0;
}

// ---- MFMA GEMM: out[m,n] = act(A(bf16) @ W(bf16 [N][K])^T + b1 + b2) ----
__global__ __launch_bounds__(256) void k_gemm(
    const u16* __restrict__ A, int lda,
    const u16* __restrict__ W, int K,
    const float* __restrict__ bias1, const float* __restrict__ bias2,
    void* __restrict__ out, int ldo, int kc_cnt, int do_relu, int out_half)
{
    __shared__ u16 sA[64*40];
    __shared__ u16 sB[256*40];
    int tid = threadIdx.x;
    int w = tid >> 6, lane = tid & 63, q = lane >> 4, r = lane & 15;
    int m0 = blockIdx.x * 64;
    int n0 = blockIdx.y * 256;

    f32x4 acc[4][4];
    for (int a_ = 0; a_ < 4; a_++)
        for (int b_ = 0; b_ < 4; b_++){
            acc[a_][b_][0] = 0.f; acc[a_][b_][1] = 0.f;
            acc[a_][b_][2] = 0.f; acc[a_][b_][3] = 0.f;
        }

    for (int kc = 0; kc < kc_cnt; kc++){
        {
            int row = tid >> 2, seg = tid & 3;
            uint4 v = *(const uint4*)(A + (size_t)(m0+row)*lda + kc*32 + seg*8);
            *(uint4*)(&sA[row*40 + seg*8]) = v;
            const u16* wr = W + (size_t)(n0 + tid)*K + kc*32;
            uint4 b0 = *(const uint4*)(wr);
            uint4 b1 = *(const uint4*)(wr+8);
            uint4 b2 = *(const uint4*)(wr+16);
            uint4 b3 = *(const uint4*)(wr+24);
            u16* d = &sB[tid*40];
            *(uint4*)(d)    = b0; *(uint4*)(d+8)  = b1;
            *(uint4*)(d+16) = b2; *(uint4*)(d+24) = b3;
        }
        __syncthreads();
        bf16x8 a[4], b[4];
        for (int mt = 0; mt < 4; mt++) a[mt] = *(const bf16x8*)(&sA[(mt*16 + r)*40 + q*8]);
        for (int i = 0; i < 4; i++)    b[i]  = *(const bf16x8*)(&sB[((w*4+i)*16 + r)*40 + q*8]);
        for (int mt = 0; mt < 4; mt++)
            for (int i = 0; i < 4; i++)
                acc[mt][i] = __builtin_amdgcn_mfma_f32_16x16x32_bf16(a[mt], b[i], acc[mt][i], 0, 0, 0);
        __syncthreads();
    }

    for (int i = 0; i < 4; i++){
        int n = n0 + (w*4+i)*16 + r;
        float bs = 0.f;
        if (bias1) bs += bias1[n];
        if (bias2) bs += bias2[n];
        for (int mt = 0; mt < 4; mt++){
            for (int reg = 0; reg < 4; reg++){
                int m = m0 + mt*16 + q*4 + reg;
                float v = acc[mt][i][reg] + bs;
                if (do_relu) v = fmaxf(v, 0.f);
                if (out_half) ((_Float16*)out)[(size_t)m*ldo + n] = (_Float16)v;
                else          ((u16*)out)[(size_t)m*ldo + n] = f2bf(v);
            }
        }
    }
}

// ---- zero barrier flags (F0x[0..2048), F1x[2048..4096)) ----
__global__ void k_zcnt(int* bar){
    int i = blockIdx.x*256 + threadIdx.x;
    if (i < 4096)
        __hip_atomic_store(&bar[i], 0, __ATOMIC_RELAXED, __HIP_MEMORY_SCOPE_AGENT);
}

// ---- FUSED two-layer recurrence v11: ALL-SC1 (sc0 refuted by R8 fail) ----
// grid 256 = 2 layers x (4 m-groups x 32 j-blocks). 1 block/CU, 128KB LDS.
// vs v9 (verified 1108us):
//  (a) L1 split-wait: the Whh*h1(t) MFMA pass runs AFTER the peer flag, under the
//      wait for L0's next flag -> off the serial chain. L1 in-round = 1 MFMA pass.
//  (b) h0 depth-4 ring replaces {h0A,h0B + x0r}: L0 stores h0(t) ONCE (pre-relu);
//      L1 loads the same words and applies relu in-register (exact bf16 bit trick).
//      Halves L0 store traffic. Same flag protocol + depth-4 backpressure (thr t-1).
// All h/flag traffic: relaxed AGENT (SC1, coherence point) - the proven protocol.
__global__ __launch_bounds__(256, 1) void k_rec2(
    const u16* __restrict__ Whhb,      // bf16 [2][2048][512]
    const u16* __restrict__ Wihb1,     // bf16 [2048][512] layer-1 slice
    const _Float16* __restrict__ xw,   // [MTOT][2048] layer-0 addends (biases folded)
    const float* __restrict__ bih, const float* __restrict__ bhh,  // [2][2048]
    u64* __restrict__ h0r,             // [4][256][128] u64 ring (h0, bf16, pre-relu)
    u64* __restrict__ h1A, u64* __restrict__ h1B,
    int* __restrict__ bar)
{
    extern __shared__ u16 smem[];      // 131072 B dynamic
    int tid = threadIdx.x;
    int w = tid >> 6, lane = tid & 63, q = lane >> 4, r = lane & 15;
    int lay  = blockIdx.x >> 7;
    int bid7 = blockIdx.x & 127;
    int mg = bid7 & 3, jb = bid7 >> 2;
    int m0 = mg*64, j0 = jb*16;
    int j = j0 + r;
    int* F0x = bar;
    int* F1x = bar + 2048;
    int fidx = (mg*GRPB + jb)*FS;

    {   // stage weights: Whh slice (and Wih slice for layer 1), XOR-swizzled
        int row = tid >> 2, seg = tid & 3;
        int g = row >> 4, jj = row & 15;
        const u16* srcW = Whhb + (size_t)lay*G4*HH + (size_t)(g*HH + j0 + jj)*HH;
        u16* sW = smem + (lay ? 64*512 : 0);
        for (int i = 0; i < 16; i++){
            int c = seg*16 + i;
            *(uint4*)(&sW[row*512 + ((c ^ (row & 7)) * 8)]) = *(const uint4*)(srcW + c*8);
        }
        if (lay){
            const u16* srcI = Wihb1 + (size_t)(g*HH + j0 + jj)*HH;
            for (int i = 0; i < 16; i++){
                int c = seg*16 + i;
                *(uint4*)(&smem[row*512 + ((c ^ (row & 7)) * 8)]) = *(const uint4*)(srcI + c*8);
            }
        }
    }
    float creg[4] = {0.f, 0.f, 0.f, 0.f};
    // L0 zeroes ring slot 3 (= h0(-1), read at t=0)
    if (!lay && (r & 3) == 0){
        u64* hz = h0r + (size_t)3*BB*(HH/4);
        for (int reg = 0; reg < 4; reg++){
            int m = m0 + w*16 + q*4 + reg;
            __hip_atomic_store(&hz[(size_t)m*(HH/4) + ((j0 + r) >> 2)], 0ULL,
                               __ATOMIC_RELAXED, __HIP_MEMORY_SCOPE_AGENT);
        }
    }
    asm volatile("s_waitcnt vmcnt(0)" ::: "memory");
    __syncthreads();   // prologue stores drained; sB staged
    if (tid == 0)
        __hip_atomic_store(lay ? &F1x[fidx] : &F0x[fidx], 1,
                           __ATOMIC_RELAXED, __HIP_MEMORY_SCOPE_AGENT);
    if (tid < GRPB){
        int* fp = (lay ? F1x : F0x) + (mg*GRPB + tid)*FS;
        long long t0c = clock64();
        while (__hip_atomic_load(fp, __ATOMIC_RELAXED, __HIP_MEMORY_SCOPE_AGENT) < 1){
            __builtin_amdgcn_s_sleep(1);
            if (clock64() - t0c > 50000000LL) break;
        }
    }
    __syncthreads();

    if (!lay){
        // ======================= LAYER 0 =======================
        float xnxt[4][4];
        #pragma unroll
        for (int reg = 0; reg < 4; reg++){
            int m = m0 + w*16 + q*4 + reg;
            const _Float16* xr = xw + ((size_t)m*TT + 0)*G4 + j;
            #pragma unroll
            for (int g = 0; g < 4; g++)
                xnxt[reg][g] = (float)__builtin_nontemporal_load(xr + g*HH);
        }

        for (int t = 0; t < TT; t++){
            const u64* hsrc = h0r + (size_t)((t + 3) & 3)*BB*(HH/4);   // h0(t-1)
            u32* hdst32 = (u32*)(h0r + (size_t)(t & 3)*BB*(HH/4));     // h0(t)
            const u64* hrow = hsrc + (size_t)(m0 + w*16 + r)*(HH/4);

            float xcur[4][4];
            #pragma unroll
            for (int reg = 0; reg < 4; reg++)
                #pragma unroll
                for (int g = 0; g < 4; g++)
                    xcur[reg][g] = xnxt[reg][g];

            u64 hd[32];
            #pragma unroll
            for (int kc = 0; kc < 16; kc++){
                int jg0 = kc*8 + q*2;
                hd[kc*2]   = __hip_atomic_load(&hrow[jg0],   __ATOMIC_RELAXED, __HIP_MEMORY_SCOPE_AGENT);
                hd[kc*2+1] = __hip_atomic_load(&hrow[jg0+1], __ATOMIC_RELAXED, __HIP_MEMORY_SCOPE_AGENT);
            }
            if (t + 1 < TT){
                #pragma unroll
                for (int reg = 0; reg < 4; reg++){
                    int m = m0 + w*16 + q*4 + reg;
                    const _Float16* xr = xw + ((size_t)m*TT + (t+1))*G4 + j;
                    #pragma unroll
                    for (int g = 0; g < 4; g++)
                        xnxt[reg][g] = (float)__builtin_nontemporal_load(xr + g*HH);
                }
            }
            asm volatile("" :
                "+v"(hd[0]),  "+v"(hd[1]),  "+v"(hd[2]),  "+v"(hd[3]),
                "+v"(hd[4]),  "+v"(hd[5]),  "+v"(hd[6]),  "+v"(hd[7]),
                "+v"(hd[8]),  "+v"(hd[9]),  "+v"(hd[10]), "+v"(hd[11]),
                "+v"(hd[12]), "+v"(hd[13]), "+v"(hd[14]), "+v"(hd[15]));
            asm volatile("" :
                "+v"(hd[16]), "+v"(hd[17]), "+v"(hd[18]), "+v"(hd[19]),
                "+v"(hd[20]), "+v"(hd[21]), "+v"(hd[22]), "+v"(hd[23]),
                "+v"(hd[24]), "+v"(hd[25]), "+v"(hd[26]), "+v"(hd[27]),
                "+v"(hd[28]), "+v"(hd[29]), "+v"(hd[30]), "+v"(hd[31]));
            __builtin_amdgcn_sched_barrier(0);

            f32x4 acc[4];
            for (int g = 0; g < 4; g++){
                acc[g][0] = 0.f; acc[g][1] = 0.f; acc[g][2] = 0.f; acc[g][3] = 0.f;
            }
            #pragma unroll
            for (int kc = 0; kc < 16; kc++){
                union { u64 d[2]; bf16x8 v; } au;
                au.d[0] = hd[kc*2];
                au.d[1] = hd[kc*2+1];
                int cbase = kc*4 + q;
                #pragma unroll
                for (int g = 0; g < 4; g++){
                    int row = g*16 + r;
                    bf16x8 b = *(const bf16x8*)(&smem[row*512 + ((cbase ^ (row & 7)) * 8)]);
                    acc[g] = __builtin_amdgcn_mfma_f32_16x16x32_bf16(au.v, b, acc[g], 0, 0, 0);
                }
            }

            #pragma unroll
            for (int reg = 0; reg < 4; reg++){
                int m = m0 + w*16 + q*4 + reg;
                float Gi = acc[0][reg] + xcur[reg][0];
                float Gf = acc[1][reg] + xcur[reg][1];
                float Gg = acc[2][reg] + xcur[reg][2];
                float Go = acc[3][reg] + xcur[reg][3];
                float iv = 1.f/(1.f + __expf(-Gi));
                float fv = 1.f/(1.f + __expf(-Gf));
                float gv = fast_tanh(Gg);
                float ov = 1.f/(1.f + __expf(-Go));
                float c = fv * creg[reg] + iv * gv;
                creg[reg] = c;
                float h = ov * fast_tanh(c);
                u32 own = (u32)f2bf(h);
                u32 p01 = own | (((u32)__shfl_xor((int)own, 1)) << 16);
                if ((r & 1) == 0){
                    __hip_atomic_store(&hdst32[(size_t)m*(HH/2) + ((j0 + r) >> 1)], p01,
                                       __ATOMIC_RELAXED, __HIP_MEMORY_SCOPE_AGENT);
                }
            }

            asm volatile("s_waitcnt vmcnt(0)" ::: "memory");
            __syncthreads();
            if (tid == 0)
                __hip_atomic_store(&F0x[fidx], t + 2, __ATOMIC_RELAXED, __HIP_MEMORY_SCOPE_AGENT);
            if (t + 1 < TT){
                if (tid < 64){
                    long long t0c = clock64();
                    const int* fp; int thr;
                    if (lane < GRPB){ fp = &F0x[(mg*GRPB + lane)*FS];        thr = t + 2; }
                    else            { fp = &F1x[(mg*GRPB + (lane-GRPB))*FS]; thr = t - 1; }
                    while (__hip_atomic_load(fp, __ATOMIC_RELAXED, __HIP_MEMORY_SCOPE_AGENT) < thr){
                        __builtin_amdgcn_s_sleep(1);
                        if (clock64() - t0c > 50000000LL) break;
                    }
                }
                __syncthreads();
            }
        }
    } else {
        // ======================= LAYER 1 =======================
        const u16* sWih = smem;
        const u16* sWhh = smem + 64*512;
        float bs1[4];
        for (int g = 0; g < 4; g++)
            bs1[g] = bih[G4 + g*HH + j] + bhh[G4 + g*HH + j];

        // wait h0(0) visible (L0 round 0 done)
        if (tid < GRPB){
            const int* fp = &F0x[(mg*GRPB + tid)*FS];
            long long t0c = clock64();
            while (__hip_atomic_load(fp, __ATOMIC_RELAXED, __HIP_MEMORY_SCOPE_AGENT) < 2){
                __builtin_amdgcn_s_sleep(1);
                if (clock64() - t0c > 50000000LL) break;
            }
        }
        __syncthreads();

        f32x4 acc_hh[4];   // Whh @ h1(t-1); zero for t=0
        for (int g = 0; g < 4; g++){
            acc_hh[g][0] = 0.f; acc_hh[g][1] = 0.f; acc_hh[g][2] = 0.f; acc_hh[g][3] = 0.f;
        }

        for (int t = 0; t < TT; t++){
            const u64* xsrc = h0r + (size_t)(t & 3)*BB*(HH/4);   // h0(t), pre-relu
            u64*       hdst = (t & 1) ? h1A : h1B;               // t=99 -> h1A
            const u64* xrow = xsrc + (size_t)(m0 + w*16 + r)*(HH/4);

            // ---- Wih pass on relu(h0(t)) ----
            u64 hx[32];
            #pragma unroll
            for (int kc = 0; kc < 16; kc++){
                int jg0 = kc*8 + q*2;
                hx[kc*2]   = relu4_bf16(__hip_atomic_load(&xrow[jg0],   __ATOMIC_RELAXED, __HIP_MEMORY_SCOPE_AGENT));
                hx[kc*2+1] = relu4_bf16(__hip_atomic_load(&xrow[jg0+1], __ATOMIC_RELAXED, __HIP_MEMORY_SCOPE_AGENT));
            }
            asm volatile("" :
                "+v"(hx[0]),  "+v"(hx[1]),  "+v"(hx[2]),  "+v"(hx[3]),
                "+v"(hx[4]),  "+v"(hx[5]),  "+v"(hx[6]),  "+v"(hx[7]),
                "+v"(hx[8]),  "+v"(hx[9]),  "+v"(hx[10]), "+v"(hx[11]),
                "+v"(hx[12]), "+v"(hx[13]), "+v"(hx[14]), "+v"(hx[15]));
            asm volatile("" :
                "+v"(hx[16]), "+v"(hx[17]), "+v"(hx[18]), "+v"(hx[19]),
                "+v"(hx[20]), "+v"(hx[21]), "+v"(hx[22]), "+v"(hx[23]),
                "+v"(hx[24]), "+v"(hx[25]), "+v"(hx[26]), "+v"(hx[27]),
                "+v"(hx[28]), "+v"(hx[29]), "+v"(hx[30]), "+v"(hx[31]));
            __builtin_amdgcn_sched_barrier(0);

            f32x4 acc[4];
            for (int g = 0; g < 4; g++) acc[g] = acc_hh[g];
            #pragma unroll
            for (int kc = 0; kc < 16; kc++){
                union { u64 d[2]; bf16x8 v; } au;
                au.d[0] = hx[kc*2];
                au.d[1] = hx[kc*2+1];
                int cbase = kc*4 + q;
                #pragma unroll
                for (int g = 0; g < 4; g++){
                    int row = g*16 + r;
                    bf16x8 b = *(const bf16x8*)(&sWih[row*512 + ((cbase ^ (row & 7)) * 8)]);
                    acc[g] = __builtin_amdgcn_mfma_f32_16x16x32_bf16(au.v, b, acc[g], 0, 0, 0);
                }
            }

            u32* hdst32 = (u32*)hdst;
            #pragma unroll
            for (int reg = 0; reg < 4; reg++){
                int m = m0 + w*16 + q*4 + reg;
                float Gi = acc[0][reg] + bs1[0];
                float Gf = acc[1][reg] + bs1[1];
                float Gg = acc[2][reg] + bs1[2];
                float Go = acc[3][reg] + bs1[3];
                float iv = 1.f/(1.f + __expf(-Gi));
                float fv = 1.f/(1.f + __expf(-Gf));
                float gv = fast_tanh(Gg);
                float ov = 1.f/(1.f + __expf(-Go));
                float c = fv * creg[reg] + iv * gv;
                creg[reg] = c;
                float h = ov * fast_tanh(c);
                u32 own = (u32)f2bf(h);
                u32 p01 = own | (((u32)__shfl_xor((int)own, 1)) << 16);
                if ((r & 1) == 0){
                    __hip_atomic_store(&hdst32[(size_t)m*(HH/2) + ((j0 + r) >> 1)], p01,
                                       __ATOMIC_RELAXED, __HIP_MEMORY_SCOPE_AGENT);
                }
            }

            asm volatile("s_waitcnt vmcnt(0)" ::: "memory");
            __syncthreads();
            if (tid == 0)
                __hip_atomic_store(&F1x[fidx], t + 2, __ATOMIC_RELAXED, __HIP_MEMORY_SCOPE_AGENT);

            if (t + 1 < TT){
                // peer wait: h1(t) visible from all 32 j-blocks
                if (tid < GRPB){
                    const int* fp = &F1x[(mg*GRPB + tid)*FS];
                    long long t0c = clock64();
                    while (__hip_atomic_load(fp, __ATOMIC_RELAXED, __HIP_MEMORY_SCOPE_AGENT) < t + 2){
                        __builtin_amdgcn_s_sleep(1);
                        if (clock64() - t0c > 50000000LL) break;
                    }
                }
                __syncthreads();

                // Whh pass for t+1 — off the serial chain (runs under the F0 wait)
                const u64* hrow = hdst + (size_t)(m0 + w*16 + r)*(HH/4);
                u64 hh[32];
                #pragma unroll
                for (int kc = 0; kc < 16; kc++){
                    int jg0 = kc*8 + q*2;
                    hh[kc*2]   = __hip_atomic_load(&hrow[jg0],   __ATOMIC_RELAXED, __HIP_MEMORY_SCOPE_AGENT);
                    hh[kc*2+1] = __hip_atomic_load(&hrow[jg0+1], __ATOMIC_RELAXED, __HIP_MEMORY_SCOPE_AGENT);
                }
                asm volatile("" :
                    "+v"(hh[0]),  "+v"(hh[1]),  "+v"(hh[2]),  "+v"(hh[3]),
                    "+v"(hh[4]),  "+v"(hh[5]),  "+v"(hh[6]),  "+v"(hh[7]),
                    "+v"(hh[8]),  "+v"(hh[9]),  "+v"(hh[10]), "+v"(hh[11]),
                    "+v"(hh[12]), "+v"(hh[13]), "+v"(hh[14]), "+v"(hh[15]));
                asm volatile("" :
                    "+v"(hh[16]), "+v"(hh[17]), "+v"(hh[18]), "+v"(hh[19]),
                    "+v"(hh[20]), "+v"(hh[21]), "+v"(hh[22]), "+v"(hh[23]),
                    "+v"(hh[24]), "+v"(hh[25]), "+v"(hh[26]), "+v"(hh[27]),
                    "+v"(hh[28]), "+v"(hh[29]), "+v"(hh[30]), "+v"(hh[31]));
                __builtin_amdgcn_sched_barrier(0);

                for (int g = 0; g < 4; g++){
                    acc_hh[g][0] = 0.f; acc_hh[g][1] = 0.f;
                    acc_hh[g][2] = 0.f; acc_hh[g][3] = 0.f;
                }
                #pragma unroll
                for (int kc = 0; kc < 16; kc++){
                    union { u64 d[2]; bf16x8 v; } au;
                    au.d[0] = hh[kc*2];
                    au.d[1] = hh[kc*2+1];
                    int cbase = kc*4 + q;
                    #pragma unroll
                    for (int g = 0; g < 4; g++){
                        int row = g*16 + r;
                        bf16x8 b = *(const bf16x8*)(&sWhh[row*512 + ((cbase ^ (row & 7)) * 8)]);
                        acc_hh[g] = __builtin_amdgcn_mfma_f32_16x16x32_bf16(au.v, b, acc_hh[g], 0, 0, 0);
                    }
                }

                // wait h0(t+1) visible (L0 finished round t+1)
                if (tid < GRPB){
                    const int* fp = &F0x[(mg*GRPB + tid)*FS];
                    long long t0c = clock64();
                    while (__hip_atomic_load(fp, __ATOMIC_RELAXED, __HIP_MEMORY_SCOPE_AGENT) < t + 3){
                        __builtin_amdgcn_s_sleep(1);
                        if (clock64() - t0c > 50000000LL) break;
                    }
                }
                __syncthreads();
            }
        }
    }
}

// ---- heads: fp32 output (d_out is float*), zero-sentinel kept ----
__global__ void k_heads(
    const u16* __restrict__ hfin, const float* __restrict__ Wout,
    const float* __restrict__ bout, const float* __restrict__ Wcls,
    const float* __restrict__ bcls, float* __restrict__ out)
{
    __shared__ float last[HH];
    int b = blockIdx.x, tid = threadIdx.x;
    for (int h = tid; h < HH; h += 256) last[h] = fmaxf(bf2f(hfin[b*HH + h]), 0.f);
    __syncthreads();
    for (int o = tid; o < NCONT + NCAT*VV; o += 256){
        if (o < NCONT){
            float a = bout[o];
            for (int h = 0; h < HH; h++) a += last[h] * Wout[h*NCONT + o];
            out[b*NCONT + o] = (a == 0.0f) ? 7.0f : a;
        } else {
            int oc = o - NCONT;
            int n = oc >> 5, v = oc & 31;
            float a = bcls[oc];
            const float* wp = Wcls + (size_t)n*HH*VV + v;
            for (int h = 0; h < HH; h++) a += last[h] * wp[h*VV];
            out[BB*NCONT + b*(NCAT*VV) + oc] = (a == 0.0f) ? 7.0f : a;
        }
    }
}

extern "C" void kernel_launch(void* const* d_in, const int* in_sizes, int n_in,
                              void* d_out, int out_size, void* d_ws, size_t ws_size,
                              hipStream_t stream){
    const float* x      = (const float*)d_in[0];
    const float* smean  = (const float*)d_in[1];
    const float* sscale = (const float*)d_in[2];
    const float* emb    = (const float*)d_in[3];
    const float* Win    = (const float*)d_in[4];
    const float* bin    = (const float*)d_in[5];
    const float* Wih    = (const float*)d_in[6];
    const float* Whh    = (const float*)d_in[7];
    const float* bih    = (const float*)d_in[8];
    const float* bhh    = (const float*)d_in[9];
    const float* Wout   = (const float*)d_in[10];
    const float* bout   = (const float*)d_in[11];
    const float* Wcls   = (const float*)d_in[12];
    const float* bcls   = (const float*)d_in[13];
    (void)in_sizes; (void)n_in; (void)out_size;

    char* ws = (char*)d_ws;
    size_t off = 0;
    u16*      feat  = (u16*)(ws + off);      off += (size_t)MTOT*KIN*2;   //   9.8 MB
    u16*      WinTb = (u16*)(ws + off);      off += (size_t)HH*KIN*2;     //   0.2 MB
    u16*      Xbuf  = (u16*)(ws + off);      off += (size_t)MTOT*HH*2;    //  26.2 MB
    _Float16* xw    = (_Float16*)(ws + off); off += (size_t)MTOT*G4*2;    // 104.9 MB
    u16*      Wihb  = (u16*)(ws + off);      off += (size_t)2*G4*HH*2;    //   4.2 MB
    u16*      Whhb  = (u16*)(ws + off);      off += (size_t)2*G4*HH*2;    //   4.2 MB
    u64*      h0r   = (u64*)(ws + off);      off += (size_t)4*BB*HH*2;    //   1.0 MB
    u64*      h1A   = (u64*)(ws + off);      off += (size_t)BB*HH*2;
    u64*      h1B   = (u64*)(ws + off);      off += (size_t)BB*HH*2;
    int*      bar   = (int*)(ws + off);      off += 4096*4;               //  16 KB
    (void)off; (void)ws_size;

    // weight prep (bf16 once)
    PredictionModel_58841051955204_kernel<<<384, 256, 0, stream>>>(Win, WinTb);
    k_cvt<<<8192, 256, 0, stream>>>(Wih, Wihb, 2*G4*HH);
    k_cvt<<<8192, 256, 0, stream>>>(Whh, Whhb, 2*G4*HH);

    k_feat<<<1600, 256, 0, stream>>>(x, smean, sscale, emb, feat);
    // h0 input = relu(feat @ W_in + b_in) -> Xbuf (bf16)
    k_gemm<<<dim3(400, 2), 256, 0, stream>>>(feat, KIN, WinTb, KIN, bin, (const float*)0,
                                             Xbuf, HH, 6, 1, 0);
    // xw (layer 0 only) = Xbuf @ Wih_0^T + bih_0 + bhh_0 -> fp16
    k_gemm<<<dim3(400, 8), 256, 0, stream>>>(Xbuf, HH, Wihb, HH, bih, bhh,
                                             xw, G4, 16, 0, 1);
    k_zcnt<<<16, 256, 0, stream>>>(bar);
    // fused both-layer recurrence (all SC1)
    k_rec2<<<256, 256, 131072, stream>>>(Whhb, Wihb + (size_t)G4*HH, xw, bih, bhh,
                                         h0r, h1A, h1B, bar);
    // T=100 even: layer-1 t=99 (odd) stores to h1A; heads write fp32 d_out
    k_heads<<<256, 256, 0, stream>>>((const u16*)h1A, Wout, bout, Wcls, bcls, (float*)d_out);
}

// Round 10
// 1350.536 us; speedup vs baseline: 1.1367x; 1.1367x over previous
//
#include <hip/hip_runtime.h>

#define BB 256
#define TT 100
#define HH 512
#define G4 2048
#define INL 176
#define KIN 192
#define NCAT 16
#define NCONT 48
#define VV 32
#define EE 8
#define MTOT (BB*TT)
#define GRPB 32   // j-blocks per m-group
#define FS 16     // flag stride in ints (64B)

typedef unsigned short u16;
typedef unsigned int   u32;
typedef unsigned long long u64;
typedef __attribute__((ext_vector_type(8))) short bf16x8;
typedef __attribute__((ext_vector_type(4))) float f32x4;

__device__ __forceinline__ float bf2f(u16 u){
    union { u32 i; float f; } v; v.i = ((u32)u) << 16; return v.f;
}
__device__ __forceinline__ u16 f2bf(float f){
    union { float f; u32 i; } v; v.f = f;
    u32 b = v.i;
    b += 0x7FFFu + ((b >> 16) & 1u);   // round-to-nearest-even
    return (u16)(b >> 16);
}
// exact identity tanh(x) = 1 - 2/(e^{2x}+1); __expf precision << bf16 rounding
__device__ __forceinline__ float fast_tanh(float x){
    float e = __expf(2.f * x);
    return 1.f - 2.f / (e + 1.f);
}
// packed relu on 4 bf16 halves: zero any half with sign bit set (exact)
__device__ __forceinline__ u64 relu4_bf16(u64 v){
    u64 s = v & 0x8000800080008000ULL;
    u64 m = s - (s >> 15);            // 0x7FFF per negative half (no cross-half borrow)
    return v & ~(s | m);
}

// ---- canonical-name kernel: W_in fp32 [176][512] -> bf16 WinT [512][192] (pad) ----
__global__ void PredictionModel_58841051955204_kernel(
    const float* __restrict__ Win, u16* __restrict__ WinT){
    int idx = blockIdx.x*256 + threadIdx.x;
    if (idx >= HH*KIN) return;
    int h = idx / KIN, i = idx % KIN;
    WinT[idx] = (i < INL) ? f2bf(Win[i*HH + h]) : (u16)0;
}

// ---- bulk fp32 -> bf16 convert (weights) ----
__global__ void k_cvt(const float* __restrict__ in, u16* __restrict__ out, int n){
    int i = blockIdx.x*256 + threadIdx.x;
    if (i < n) out[i] = f2bf(in[i]);
}

// ---- featurize: fp32 inputs -> bf16 feat [25600][192] ----
__global__ void k_feat(const float* __restrict__ x, const float* __restrict__ mean,
                       const float* __restrict__ scale, const float* __restrict__ emb,
                       u16* __restrict__ feat){
    int idx = blockIdx.x*256 + threadIdx.x;
    int bt = idx >> 4, g = idx & 15;
    if (bt >= MTOT) return;
    const float* xr = x + (size_t)bt*64;
    u16* fr = feat + (size_t)bt*KIN;
    int k0 = g*4;
    int ci = (int)xr[k0];
    if (ci < 0) ci = 0;
    if (ci > VV-1) ci = VV-1;
    const float* ep = emb + (size_t)(g*VV + ci)*EE;
    int c0 = g*11;
    for (int e = 0; e < 8; e++) fr[c0+e] = f2bf(ep[e]);
    for (int j = 1; j <= 3; j++){
        int k = k0 + j;
        fr[c0 + 8 + (j-1)] = f2bf((xr[k] - mean[k]) / scale[k]);
    }
    fr[INL + g] = 0;
}

// ---- MFMA GEMM: out[m,n] = act(A(bf16) @ W(bf16 [N][K])^T + b1 + b2) ----
__global__ __launch_bounds__(256) void k_gemm(
    const u16* __restrict__ A, int lda,
    const u16* __restrict__ W, int K,
    const float* __restrict__ bias1, const float* __restrict__ bias2,
    void* __restrict__ out, int ldo, int kc_cnt, int do_relu, int out_half)
{
    __shared__ u16 sA[64*40];
    __shared__ u16 sB[256*40];
    int tid = threadIdx.x;
    int w = tid >> 6, lane = tid & 63, q = lane >> 4, r = lane & 15;
    int m0 = blockIdx.x * 64;
    int n0 = blockIdx.y * 256;

    f32x4 acc[4][4];
    for (int a_ = 0; a_ < 4; a_++)
        for (int b_ = 0; b_ < 4; b_++){
            acc[a_][b_][0] = 0.f; acc[a_][b_][1] = 0.f;
            acc[a_][b_][2] = 0.f; acc[a_][b_][3] = 0.f;
        }

    for (int kc = 0; kc < kc_cnt; kc++){
        {
            int row = tid >> 2, seg = tid & 3;
            uint4 v = *(const uint4*)(A + (size_t)(m0+row)*lda + kc*32 + seg*8);
            *(uint4*)(&sA[row*40 + seg*8]) = v;
            const u16* wr = W + (size_t)(n0 + tid)*K + kc*32;
            uint4 b0 = *(const uint4*)(wr);
            uint4 b1 = *(const uint4*)(wr+8);
            uint4 b2 = *(const uint4*)(wr+16);
            uint4 b3 = *(const uint4*)(wr+24);
            u16* d = &sB[tid*40];
            *(uint4*)(d)    = b0; *(uint4*)(d+8)  = b1;
            *(uint4*)(d+16) = b2; *(uint4*)(d+24) = b3;
        }
        __syncthreads();
        bf16x8 a[4], b[4];
        for (int mt = 0; mt < 4; mt++) a[mt] = *(const bf16x8*)(&sA[(mt*16 + r)*40 + q*8]);
        for (int i = 0; i < 4; i++)    b[i]  = *(const bf16x8*)(&sB[((w*4+i)*16 + r)*40 + q*8]);
        for (int mt = 0; mt < 4; mt++)
            for (int i = 0; i < 4; i++)
                acc[mt][i] = __builtin_amdgcn_mfma_f32_16x16x32_bf16(a[mt], b[i], acc[mt][i], 0, 0, 0);
        __syncthreads();
    }

    for (int i = 0; i < 4; i++){
        int n = n0 + (w*4+i)*16 + r;
        float bs = 0.f;
        if (bias1) bs += bias1[n];
        if (bias2) bs += bias2[n];
        for (int mt = 0; mt < 4; mt++){
            for (int reg = 0; reg < 4; reg++){
                int m = m0 + mt*16 + q*4 + reg;
                float v = acc[mt][i][reg] + bs;
                if (do_relu) v = fmaxf(v, 0.f);
                if (out_half) ((_Float16*)out)[(size_t)m*ldo + n] = (_Float16)v;
                else          ((u16*)out)[(size_t)m*ldo + n] = f2bf(v);
            }
        }
    }
}

// ---- zero barrier flags (F0x[0..2048), F1x[2048..4096)) ----
__global__ void k_zcnt(int* bar){
    int i = blockIdx.x*256 + threadIdx.x;
    if (i < 4096)
        __hip_atomic_store(&bar[i], 0, __ATOMIC_RELAXED, __HIP_MEMORY_SCOPE_AGENT);
}

// ---- FUSED two-layer recurrence v12 ----
// grid 256 = 2 layers x (4 m-groups x 32 j-blocks). 1 block/CU, 128KB LDS.
// vs v9 (verified 1108us k_rec2):
//  (a) BOTH layers now have Wih+Whh LDS-resident (64KB+64KB). L0 streams x(t) from
//      Xbuf directly (static data, NO flag dependency, prefetched 1 round ahead) and
//      computes gates in-kernel -> the 105MB xw buffer + its GEMM dispatch DELETED.
//  (b) h0 single-store depth-4 ring (halves L0 store traffic; L1 applies relu
//      in-register, exact bf16 bit trick).
//  (c) v9's UNIFIED round restored (v11's split-wait put the h1(t) SC1 load latency
//      on L1's serial chain: 1108->1242 regression; both load batches issue together
//      at round start, one vmcnt window).
// All h/flag traffic: relaxed AGENT (SC1, coherence point) - the proven protocol.
__global__ __launch_bounds__(256, 1) void k_rec2(
    const u16* __restrict__ Wihb,      // bf16 [2][2048][512]
    const u16* __restrict__ Whhb,      // bf16 [2][2048][512]
    const u16* __restrict__ Xbuf,      // bf16 [MTOT][512] = relu(feat@Win+bin)
    const float* __restrict__ bih, const float* __restrict__ bhh,  // [2][2048]
    u64* __restrict__ h0r,             // [4][256][128] u64 ring (h0, bf16, pre-relu)
    u64* __restrict__ h1A, u64* __restrict__ h1B,
    int* __restrict__ bar)
{
    extern __shared__ u16 smem[];      // 131072 B: sWih [64*512] | sWhh [64*512]
    int tid = threadIdx.x;
    int w = tid >> 6, lane = tid & 63, q = lane >> 4, r = lane & 15;
    int lay  = blockIdx.x >> 7;
    int bid7 = blockIdx.x & 127;
    int mg = bid7 & 3, jb = bid7 >> 2;
    int m0 = mg*64, j0 = jb*16;
    int j = j0 + r;
    int* F0x = bar;
    int* F1x = bar + 2048;
    int fidx = (mg*GRPB + jb)*FS;
    const u16* sWih = smem;
    const u16* sWhh = smem + 64*512;

    {   // stage Wih + Whh slices for my layer, XOR-swizzled
        int row = tid >> 2, seg = tid & 3;
        int g = row >> 4, jj = row & 15;
        const u16* srcI = Wihb + (size_t)lay*G4*HH + (size_t)(g*HH + j0 + jj)*HH;
        const u16* srcW = Whhb + (size_t)lay*G4*HH + (size_t)(g*HH + j0 + jj)*HH;
        for (int i = 0; i < 16; i++){
            int c = seg*16 + i;
            *(uint4*)(&smem[row*512 + ((c ^ (row & 7)) * 8)]) = *(const uint4*)(srcI + c*8);
            *(uint4*)(&smem[64*512 + row*512 + ((c ^ (row & 7)) * 8)]) = *(const uint4*)(srcW + c*8);
        }
    }
    float creg[4] = {0.f, 0.f, 0.f, 0.f};
    // zero my t=0 h-source: L0 -> ring slot 3 (= h0(-1)); L1 -> h1A (= h1(-1))
    if ((r & 3) == 0){
        u64* hz = lay ? h1A : (h0r + (size_t)3*BB*(HH/4));
        for (int reg = 0; reg < 4; reg++){
            int m = m0 + w*16 + q*4 + reg;
            __hip_atomic_store(&hz[(size_t)m*(HH/4) + ((j0 + r) >> 2)], 0ULL,
                               __ATOMIC_RELAXED, __HIP_MEMORY_SCOPE_AGENT);
        }
    }
    asm volatile("s_waitcnt vmcnt(0)" ::: "memory");
    __syncthreads();   // prologue stores drained; weights staged
    if (tid == 0)
        __hip_atomic_store(lay ? &F1x[fidx] : &F0x[fidx], 1,
                           __ATOMIC_RELAXED, __HIP_MEMORY_SCOPE_AGENT);
    if (tid < GRPB){
        int* fp = (lay ? F1x : F0x) + (mg*GRPB + tid)*FS;
        long long t0c = clock64();
        while (__hip_atomic_load(fp, __ATOMIC_RELAXED, __HIP_MEMORY_SCOPE_AGENT) < 1){
            __builtin_amdgcn_s_sleep(1);
            if (clock64() - t0c > 50000000LL) break;
        }
    }
    __syncthreads();

    float bs[4];
    for (int g = 0; g < 4; g++)
        bs[g] = bih[lay*G4 + g*HH + j] + bhh[lay*G4 + g*HH + j];

    if (!lay){
        // ======================= LAYER 0 =======================
        // prefetch x(0) (static data, plain nontemporal loads)
        const u64* xb = (const u64*)Xbuf;
        u64 xn[32];
        {
            const u64* xrow = xb + ((size_t)(m0 + w*16 + r)*TT + 0)*(HH/4);
            #pragma unroll
            for (int kc = 0; kc < 16; kc++){
                int jg0 = kc*8 + q*2;
                xn[kc*2]   = __builtin_nontemporal_load(&xrow[jg0]);
                xn[kc*2+1] = __builtin_nontemporal_load(&xrow[jg0+1]);
            }
        }

        for (int t = 0; t < TT; t++){
            const u64* hsrc = h0r + (size_t)((t + 3) & 3)*BB*(HH/4);   // h0(t-1)
            u32* hdst32 = (u32*)(h0r + (size_t)(t & 3)*BB*(HH/4));     // h0(t)
            const u64* hrow = hsrc + (size_t)(m0 + w*16 + r)*(HH/4);

            u64 hd[32];
            #pragma unroll
            for (int kc = 0; kc < 16; kc++){
                int jg0 = kc*8 + q*2;
                hd[kc*2]   = __hip_atomic_load(&hrow[jg0],   __ATOMIC_RELAXED, __HIP_MEMORY_SCOPE_AGENT);
                hd[kc*2+1] = __hip_atomic_load(&hrow[jg0+1], __ATOMIC_RELAXED, __HIP_MEMORY_SCOPE_AGENT);
            }
            asm volatile("" :
                "+v"(hd[0]),  "+v"(hd[1]),  "+v"(hd[2]),  "+v"(hd[3]),
                "+v"(hd[4]),  "+v"(hd[5]),  "+v"(hd[6]),  "+v"(hd[7]),
                "+v"(hd[8]),  "+v"(hd[9]),  "+v"(hd[10]), "+v"(hd[11]),
                "+v"(hd[12]), "+v"(hd[13]), "+v"(hd[14]), "+v"(hd[15]));
            asm volatile("" :
                "+v"(hd[16]), "+v"(hd[17]), "+v"(hd[18]), "+v"(hd[19]),
                "+v"(hd[20]), "+v"(hd[21]), "+v"(hd[22]), "+v"(hd[23]),
                "+v"(hd[24]), "+v"(hd[25]), "+v"(hd[26]), "+v"(hd[27]),
                "+v"(hd[28]), "+v"(hd[29]), "+v"(hd[30]), "+v"(hd[31]));
            __builtin_amdgcn_sched_barrier(0);

            f32x4 acc[4];
            for (int g = 0; g < 4; g++){
                acc[g][0] = 0.f; acc[g][1] = 0.f; acc[g][2] = 0.f; acc[g][3] = 0.f;
            }
            // pass A: Wih0 @ x(t)   (x prefetched last round)
            #pragma unroll
            for (int kc = 0; kc < 16; kc++){
                union { u64 d[2]; bf16x8 v; } au;
                au.d[0] = xn[kc*2];
                au.d[1] = xn[kc*2+1];
                int cbase = kc*4 + q;
                #pragma unroll
                for (int g = 0; g < 4; g++){
                    int row = g*16 + r;
                    bf16x8 b = *(const bf16x8*)(&sWih[row*512 + ((cbase ^ (row & 7)) * 8)]);
                    acc[g] = __builtin_amdgcn_mfma_f32_16x16x32_bf16(au.v, b, acc[g], 0, 0, 0);
                }
            }
            // pass B: Whh0 @ h0(t-1)
            #pragma unroll
            for (int kc = 0; kc < 16; kc++){
                union { u64 d[2]; bf16x8 v; } au;
                au.d[0] = hd[kc*2];
                au.d[1] = hd[kc*2+1];
                int cbase = kc*4 + q;
                #pragma unroll
                for (int g = 0; g < 4; g++){
                    int row = g*16 + r;
                    bf16x8 b = *(const bf16x8*)(&sWhh[row*512 + ((cbase ^ (row & 7)) * 8)]);
                    acc[g] = __builtin_amdgcn_mfma_f32_16x16x32_bf16(au.v, b, acc[g], 0, 0, 0);
                }
            }
            // prefetch x(t+1) — overlaps cell + drain + poll
            if (t + 1 < TT){
                const u64* xrow = xb + ((size_t)(m0 + w*16 + r)*TT + (t+1))*(HH/4);
                #pragma unroll
                for (int kc = 0; kc < 16; kc++){
                    int jg0 = kc*8 + q*2;
                    xn[kc*2]   = __builtin_nontemporal_load(&xrow[jg0]);
                    xn[kc*2+1] = __builtin_nontemporal_load(&xrow[jg0+1]);
                }
            }

            #pragma unroll
            for (int reg = 0; reg < 4; reg++){
                int m = m0 + w*16 + q*4 + reg;
                float Gi = acc[0][reg] + bs[0];
                float Gf = acc[1][reg] + bs[1];
                float Gg = acc[2][reg] + bs[2];
                float Go = acc[3][reg] + bs[3];
                float iv = 1.f/(1.f + __expf(-Gi));
                float fv = 1.f/(1.f + __expf(-Gf));
                float gv = fast_tanh(Gg);
                float ov = 1.f/(1.f + __expf(-Go));
                float c = fv * creg[reg] + iv * gv;
                creg[reg] = c;
                float h = ov * fast_tanh(c);
                u32 own = (u32)f2bf(h);
                u32 p01 = own | (((u32)__shfl_xor((int)own, 1)) << 16);
                if ((r & 1) == 0){
                    __hip_atomic_store(&hdst32[(size_t)m*(HH/2) + ((j0 + r) >> 1)], p01,
                                       __ATOMIC_RELAXED, __HIP_MEMORY_SCOPE_AGENT);
                }
            }

            asm volatile("s_waitcnt vmcnt(0)" ::: "memory");
            __syncthreads();
            if (tid == 0)
                __hip_atomic_store(&F0x[fidx], t + 2, __ATOMIC_RELAXED, __HIP_MEMORY_SCOPE_AGENT);
            if (t + 1 < TT){
                if (tid < 64){
                    long long t0c = clock64();
                    const int* fp; int thr;
                    if (lane < GRPB){ fp = &F0x[(mg*GRPB + lane)*FS];        thr = t + 2; }  // peers
                    else            { fp = &F1x[(mg*GRPB + (lane-GRPB))*FS]; thr = t - 1; }  // ring slack
                    while (__hip_atomic_load(fp, __ATOMIC_RELAXED, __HIP_MEMORY_SCOPE_AGENT) < thr){
                        __builtin_amdgcn_s_sleep(1);
                        if (clock64() - t0c > 50000000LL) break;
                    }
                }
                __syncthreads();
            }
        }
    } else {
        // ======================= LAYER 1 =======================
        // wait h0(0) visible (L0 round 0 done)
        if (tid < GRPB){
            const int* fp = &F0x[(mg*GRPB + tid)*FS];
            long long t0c = clock64();
            while (__hip_atomic_load(fp, __ATOMIC_RELAXED, __HIP_MEMORY_SCOPE_AGENT) < 2){
                __builtin_amdgcn_s_sleep(1);
                if (clock64() - t0c > 50000000LL) break;
            }
        }
        __syncthreads();

        for (int t = 0; t < TT; t++){
            const u64* xsrc = h0r + (size_t)(t & 3)*BB*(HH/4);   // h0(t), pre-relu
            const u64* hsrc = (t & 1) ? h1B : h1A;               // h1(t-1); t=0 -> zeros
            u64*       hdst = (t & 1) ? h1A : h1B;               // t=99 -> h1A
            const u64* xrow = xsrc + (size_t)(m0 + w*16 + r)*(HH/4);
            const u64* hrow = hsrc + (size_t)(m0 + w*16 + r)*(HH/4);

            // unified round-start loads: hx + hh in ONE vmcnt window (v9 schedule)
            u64 hx[32], hh[32];
            #pragma unroll
            for (int kc = 0; kc < 16; kc++){
                int jg0 = kc*8 + q*2;
                hx[kc*2]   = relu4_bf16(__hip_atomic_load(&xrow[jg0],   __ATOMIC_RELAXED, __HIP_MEMORY_SCOPE_AGENT));
                hx[kc*2+1] = relu4_bf16(__hip_atomic_load(&xrow[jg0+1], __ATOMIC_RELAXED, __HIP_MEMORY_SCOPE_AGENT));
            }
            #pragma unroll
            for (int kc = 0; kc < 16; kc++){
                int jg0 = kc*8 + q*2;
                hh[kc*2]   = __hip_atomic_load(&hrow[jg0],   __ATOMIC_RELAXED, __HIP_MEMORY_SCOPE_AGENT);
                hh[kc*2+1] = __hip_atomic_load(&hrow[jg0+1], __ATOMIC_RELAXED, __HIP_MEMORY_SCOPE_AGENT);
            }
            asm volatile("" :
                "+v"(hx[0]),  "+v"(hx[1]),  "+v"(hx[2]),  "+v"(hx[3]),
                "+v"(hx[4]),  "+v"(hx[5]),  "+v"(hx[6]),  "+v"(hx[7]),
                "+v"(hx[8]),  "+v"(hx[9]),  "+v"(hx[10]), "+v"(hx[11]),
                "+v"(hx[12]), "+v"(hx[13]), "+v"(hx[14]), "+v"(hx[15]));
            asm volatile("" :
                "+v"(hx[16]), "+v"(hx[17]), "+v"(hx[18]), "+v"(hx[19]),
                "+v"(hx[20]), "+v"(hx[21]), "+v"(hx[22]), "+v"(hx[23]),
                "+v"(hx[24]), "+v"(hx[25]), "+v"(hx[26]), "+v"(hx[27]),
                "+v"(hx[28]), "+v"(hx[29]), "+v"(hx[30]), "+v"(hx[31]));
            asm volatile("" :
                "+v"(hh[0]),  "+v"(hh[1]),  "+v"(hh[2]),  "+v"(hh[3]),
                "+v"(hh[4]),  "+v"(hh[5]),  "+v"(hh[6]),  "+v"(hh[7]),
                "+v"(hh[8]),  "+v"(hh[9]),  "+v"(hh[10]), "+v"(hh[11]),
                "+v"(hh[12]), "+v"(hh[13]), "+v"(hh[14]), "+v"(hh[15]));
            asm volatile("" :
                "+v"(hh[16]), "+v"(hh[17]), "+v"(hh[18]), "+v"(hh[19]),
                "+v"(hh[20]), "+v"(hh[21]), "+v"(hh[22]), "+v"(hh[23]),
                "+v"(hh[24]), "+v"(hh[25]), "+v"(hh[26]), "+v"(hh[27]),
                "+v"(hh[28]), "+v"(hh[29]), "+v"(hh[30]), "+v"(hh[31]));
            __builtin_amdgcn_sched_barrier(0);

            f32x4 acc[4];
            for (int g = 0; g < 4; g++){
                acc[g][0] = 0.f; acc[g][1] = 0.f; acc[g][2] = 0.f; acc[g][3] = 0.f;
            }
            // pass A: Wih1 @ relu(h0(t))
            #pragma unroll
            for (int kc = 0; kc < 16; kc++){
                union { u64 d[2]; bf16x8 v; } au;
                au.d[0] = hx[kc*2];
                au.d[1] = hx[kc*2+1];
                int cbase = kc*4 + q;
                #pragma unroll
                for (int g = 0; g < 4; g++){
                    int row = g*16 + r;
                    bf16x8 b = *(const bf16x8*)(&sWih[row*512 + ((cbase ^ (row & 7)) * 8)]);
                    acc[g] = __builtin_amdgcn_mfma_f32_16x16x32_bf16(au.v, b, acc[g], 0, 0, 0);
                }
            }
            // pass B: Whh1 @ h1(t-1)
            #pragma unroll
            for (int kc = 0; kc < 16; kc++){
                union { u64 d[2]; bf16x8 v; } au;
                au.d[0] = hh[kc*2];
                au.d[1] = hh[kc*2+1];
                int cbase = kc*4 + q;
                #pragma unroll
                for (int g = 0; g < 4; g++){
                    int row = g*16 + r;
                    bf16x8 b = *(const bf16x8*)(&sWhh[row*512 + ((cbase ^ (row & 7)) * 8)]);
                    acc[g] = __builtin_amdgcn_mfma_f32_16x16x32_bf16(au.v, b, acc[g], 0, 0, 0);
                }
            }

            u32* hdst32 = (u32*)hdst;
            #pragma unroll
            for (int reg = 0; reg < 4; reg++){
                int m = m0 + w*16 + q*4 + reg;
                float Gi = acc[0][reg] + bs[0];
                float Gf = acc[1][reg] + bs[1];
                float Gg = acc[2][reg] + bs[2];
                float Go = acc[3][reg] + bs[3];
                float iv = 1.f/(1.f + __expf(-Gi));
                float fv = 1.f/(1.f + __expf(-Gf));
                float gv = fast_tanh(Gg);
                float ov = 1.f/(1.f + __expf(-Go));
                float c = fv * creg[reg] + iv * gv;
                creg[reg] = c;
                float h = ov * fast_tanh(c);
                u32 own = (u32)f2bf(h);
                u32 p01 = own | (((u32)__shfl_xor((int)own, 1)) << 16);
                if ((r & 1) == 0){
                    __hip_atomic_store(&hdst32[(size_t)m*(HH/2) + ((j0 + r) >> 1)], p01,
                                       __ATOMIC_RELAXED, __HIP_MEMORY_SCOPE_AGENT);
                }
            }

            asm volatile("s_waitcnt vmcnt(0)" ::: "memory");
            __syncthreads();
            if (tid == 0)
                __hip_atomic_store(&F1x[fidx], t + 2, __ATOMIC_RELAXED, __HIP_MEMORY_SCOPE_AGENT);

            if (t + 1 < TT){
                if (tid < 64){
                    long long t0c = clock64();
                    const int* fp; int thr;
                    if (lane < GRPB){ fp = &F1x[(mg*GRPB + lane)*FS];        thr = t + 2; }  // peers: h1(t)
                    else            { fp = &F0x[(mg*GRPB + (lane-GRPB))*FS]; thr = t + 3; }  // h0(t+1)
                    while (__hip_atomic_load(fp, __ATOMIC_RELAXED, __HIP_MEMORY_SCOPE_AGENT) < thr){
                        __builtin_amdgcn_s_sleep(1);
                        if (clock64() - t0c > 50000000LL) break;
                    }
                }
                __syncthreads();
            }
        }
    }
}

// ---- heads: fp32 output (d_out is float*), zero-sentinel kept ----
__global__ void k_heads(
    const u16* __restrict__ hfin, const float* __restrict__ Wout,
    const float* __restrict__ bout, const float* __restrict__ Wcls,
    const float* __restrict__ bcls, float* __restrict__ out)
{
    __shared__ float last[HH];
    int b = blockIdx.x, tid = threadIdx.x;
    for (int h = tid; h < HH; h += 256) last[h] = fmaxf(bf2f(hfin[b*HH + h]), 0.f);
    __syncthreads();
    for (int o = tid; o < NCONT + NCAT*VV; o += 256){
        if (o < NCONT){
            float a = bout[o];
            for (int h = 0; h < HH; h++) a += last[h] * Wout[h*NCONT + o];
            out[b*NCONT + o] = (a == 0.0f) ? 7.0f : a;
        } else {
            int oc = o - NCONT;
            int n = oc >> 5, v = oc & 31;
            float a = bcls[oc];
            const float* wp = Wcls + (size_t)n*HH*VV + v;
            for (int h = 0; h < HH; h++) a += last[h] * wp[h*VV];
            out[BB*NCONT + b*(NCAT*VV) + oc] = (a == 0.0f) ? 7.0f : a;
        }
    }
}

extern "C" void kernel_launch(void* const* d_in, const int* in_sizes, int n_in,
                              void* d_out, int out_size, void* d_ws, size_t ws_size,
                              hipStream_t stream){
    const float* x      = (const float*)d_in[0];
    const float* smean  = (const float*)d_in[1];
    const float* sscale = (const float*)d_in[2];
    const float* emb    = (const float*)d_in[3];
    const float* Win    = (const float*)d_in[4];
    const float* bin    = (const float*)d_in[5];
    const float* Wih    = (const float*)d_in[6];
    const float* Whh    = (const float*)d_in[7];
    const float* bih    = (const float*)d_in[8];
    const float* bhh    = (const float*)d_in[9];
    const float* Wout   = (const float*)d_in[10];
    const float* bout   = (const float*)d_in[11];
    const float* Wcls   = (const float*)d_in[12];
    const float* bcls   = (const float*)d_in[13];
    (void)in_sizes; (void)n_in; (void)out_size;

    char* ws = (char*)d_ws;
    size_t off = 0;
    u16*      feat  = (u16*)(ws + off);      off += (size_t)MTOT*KIN*2;   //   9.8 MB
    u16*      WinTb = (u16*)(ws + off);      off += (size_t)HH*KIN*2;     //   0.2 MB
    u16*      Xbuf  = (u16*)(ws + off);      off += (size_t)MTOT*HH*2;    //  26.2 MB
    u16*      Wihb  = (u16*)(ws + off);      off += (size_t)2*G4*HH*2;    //   4.2 MB
    u16*      Whhb  = (u16*)(ws + off);      off += (size_t)2*G4*HH*2;    //   4.2 MB
    u64*      h0r   = (u64*)(ws + off);      off += (size_t)4*BB*HH*2;    //   1.0 MB
    u64*      h1A   = (u64*)(ws + off);      off += (size_t)BB*HH*2;
    u64*      h1B   = (u64*)(ws + off);      off += (size_t)BB*HH*2;
    int*      bar   = (int*)(ws + off);      off += 4096*4;               //  16 KB
    (void)off; (void)ws_size;

    // weight prep (bf16 once)
    PredictionModel_58841051955204_kernel<<<384, 256, 0, stream>>>(Win, WinTb);
    k_cvt<<<8192, 256, 0, stream>>>(Wih, Wihb, 2*G4*HH);
    k_cvt<<<8192, 256, 0, stream>>>(Whh, Whhb, 2*G4*HH);

    k_feat<<<1600, 256, 0, stream>>>(x, smean, sscale, emb, feat);
    // Xbuf = relu(feat @ W_in + b_in) (bf16) — the only pre-GEMM left
    k_gemm<<<dim3(400, 2), 256, 0, stream>>>(feat, KIN, WinTb, KIN, bin, (const float*)0,
                                             Xbuf, HH, 6, 1, 0);
    k_zcnt<<<16, 256, 0, stream>>>(bar);
    // fused both-layer recurrence; L0 streams x from Xbuf (xw GEMM deleted)
    k_rec2<<<256, 256, 131072, stream>>>(Wihb, Whhb, Xbuf, bih, bhh,
                                         h0r, h1A, h1B, bar);
    // T=100 even: layer-1 t=99 (odd) stores to h1A; heads write fp32 d_out
    k_heads<<<256, 256, 0, stream>>>((const u16*)h1A, Wout, bout, Wcls, bcls, (float*)d_out);
}

// Round 11
// 1293.164 us; speedup vs baseline: 1.1871x; 1.0444x over previous
//
#include <hip/hip_runtime.h>

#define BB 256
#define TT 100
#define HH 512
#define G4 2048
#define INL 176
#define KIN 192
#define NCAT 16
#define NCONT 48
#define VV 32
#define EE 8
#define MTOT (BB*TT)
#define GRPB 32   // j-blocks per m-group
#define FS 16     // flag stride in ints (64B)
#define NW (2*2*G4*HH)   // per-matrix cvt span

typedef unsigned short u16;
typedef unsigned int   u32;
typedef unsigned long long u64;
typedef __attribute__((ext_vector_type(8))) short bf16x8;
typedef __attribute__((ext_vector_type(4))) float f32x4;

__device__ __forceinline__ float bf2f(u16 u){
    union { u32 i; float f; } v; v.i = ((u32)u) << 16; return v.f;
}
__device__ __forceinline__ u16 f2bf(float f){
    union { float f; u32 i; } v; v.f = f;
    u32 b = v.i;
    b += 0x7FFFu + ((b >> 16) & 1u);   // round-to-nearest-even
    return (u16)(b >> 16);
}
// exact identity tanh(x) = 1 - 2/(e^{2x}+1); __expf precision << bf16 rounding
__device__ __forceinline__ float fast_tanh(float x){
    float e = __expf(2.f * x);
    return 1.f - 2.f / (e + 1.f);
}
// packed relu on 4 bf16 halves: zero any half with sign bit set (exact)
__device__ __forceinline__ u64 relu4_bf16(u64 v){
    u64 s = v & 0x8000800080008000ULL;
    u64 m = s - (s >> 15);            // 0x7FFF per negative half (no cross-half borrow)
    return v & ~(s | m);
}

// ---- canonical-name kernel: fused weight prep ----
// idx < HH*KIN:                WinT (transpose+pad, fp32->bf16)
// next 2*G4*HH:                Wih cvt
// next 2*G4*HH:                Whh cvt
__global__ void PredictionModel_58841051955204_kernel(
    const float* __restrict__ Win, u16* __restrict__ WinT,
    const float* __restrict__ Wih, u16* __restrict__ Wihb,
    const float* __restrict__ Whh, u16* __restrict__ Whhb){
    int idx = blockIdx.x*256 + threadIdx.x;
    if (idx < HH*KIN){
        int h = idx / KIN, i = idx % KIN;
        WinT[idx] = (i < INL) ? f2bf(Win[i*HH + h]) : (u16)0;
        return;
    }
    int c1 = idx - HH*KIN;
    if (c1 < 2*G4*HH){ Wihb[c1] = f2bf(Wih[c1]); return; }
    int c2 = c1 - 2*G4*HH;
    if (c2 < 2*G4*HH) Whhb[c2] = f2bf(Whh[c2]);
}

// ---- featurize: fp32 inputs -> bf16 feat [25600][192]; block 0 also zeros bar ----
__global__ void k_feat(const float* __restrict__ x, const float* __restrict__ mean,
                       const float* __restrict__ scale, const float* __restrict__ emb,
                       u16* __restrict__ feat, int* __restrict__ bar){
    if (blockIdx.x == 0){
        for (int i = threadIdx.x; i < 4096; i += 256)
            __hip_atomic_store(&bar[i], 0, __ATOMIC_RELAXED, __HIP_MEMORY_SCOPE_AGENT);
    }
    int idx = blockIdx.x*256 + threadIdx.x;
    int bt = idx >> 4, g = idx & 15;
    if (bt >= MTOT) return;
    const float* xr = x + (size_t)bt*64;
    u16* fr = feat + (size_t)bt*KIN;
    int k0 = g*4;
    int ci = (int)xr[k0];
    if (ci < 0) ci = 0;
    if (ci > VV-1) ci = VV-1;
    const float* ep = emb + (size_t)(g*VV + ci)*EE;
    int c0 = g*11;
    for (int e = 0; e < 8; e++) fr[c0+e] = f2bf(ep[e]);
    for (int j = 1; j <= 3; j++){
        int k = k0 + j;
        fr[c0 + 8 + (j-1)] = f2bf((xr[k] - mean[k]) / scale[k]);
    }
    fr[INL + g] = 0;
}

// ---- MFMA GEMM: out[m,n] = act(A(bf16) @ W(bf16 [N][K])^T + b1 + b2) ----
__global__ __launch_bounds__(256) void k_gemm(
    const u16* __restrict__ A, int lda,
    const u16* __restrict__ W, int K,
    const float* __restrict__ bias1, const float* __restrict__ bias2,
    void* __restrict__ out, int ldo, int kc_cnt, int do_relu, int out_half)
{
    __shared__ u16 sA[64*40];
    __shared__ u16 sB[256*40];
    int tid = threadIdx.x;
    int w = tid >> 6, lane = tid & 63, q = lane >> 4, r = lane & 15;
    int m0 = blockIdx.x * 64;
    int n0 = blockIdx.y * 256;

    f32x4 acc[4][4];
    for (int a_ = 0; a_ < 4; a_++)
        for (int b_ = 0; b_ < 4; b_++){
            acc[a_][b_][0] = 0.f; acc[a_][b_][1] = 0.f;
            acc[a_][b_][2] = 0.f; acc[a_][b_][3] = 0.f;
        }

    for (int kc = 0; kc < kc_cnt; kc++){
        {
            int row = tid >> 2, seg = tid & 3;
            uint4 v = *(const uint4*)(A + (size_t)(m0+row)*lda + kc*32 + seg*8);
            *(uint4*)(&sA[row*40 + seg*8]) = v;
            const u16* wr = W + (size_t)(n0 + tid)*K + kc*32;
            uint4 b0 = *(const uint4*)(wr);
            uint4 b1 = *(const uint4*)(wr+8);
            uint4 b2 = *(const uint4*)(wr+16);
            uint4 b3 = *(const uint4*)(wr+24);
            u16* d = &sB[tid*40];
            *(uint4*)(d)    = b0; *(uint4*)(d+8)  = b1;
            *(uint4*)(d+16) = b2; *(uint4*)(d+24) = b3;
        }
        __syncthreads();
        bf16x8 a[4], b[4];
        for (int mt = 0; mt < 4; mt++) a[mt] = *(const bf16x8*)(&sA[(mt*16 + r)*40 + q*8]);
        for (int i = 0; i < 4; i++)    b[i]  = *(const bf16x8*)(&sB[((w*4+i)*16 + r)*40 + q*8]);
        for (int mt = 0; mt < 4; mt++)
            for (int i = 0; i < 4; i++)
                acc[mt][i] = __builtin_amdgcn_mfma_f32_16x16x32_bf16(a[mt], b[i], acc[mt][i], 0, 0, 0);
        __syncthreads();
    }

    for (int i = 0; i < 4; i++){
        int n = n0 + (w*4+i)*16 + r;
        float bs = 0.f;
        if (bias1) bs += bias1[n];
        if (bias2) bs += bias2[n];
        for (int mt = 0; mt < 4; mt++){
            for (int reg = 0; reg < 4; reg++){
                int m = m0 + mt*16 + q*4 + reg;
                float v = acc[mt][i][reg] + bs;
                if (do_relu) v = fmaxf(v, 0.f);
                if (out_half) ((_Float16*)out)[(size_t)m*ldo + n] = (_Float16)v;
                else          ((u16*)out)[(size_t)m*ldo + n] = f2bf(v);
            }
        }
    }
}

// ---- FUSED two-layer recurrence v13 ----
// grid 256 = 2 layers x (4 m-groups x 32 j-blocks). 1 block/CU, 128KB LDS.
// vs v12 (k_rec2 1213us): LOAD-ISSUE SCHEDULING fixes.
//  (a) L0: hd loads issued FIRST, then pass A (pure-reg x MFMAs) runs while they
//      fly; fence hd only before pass B. x(t+1) prefetch issues BETWEEN the passes
//      so it completes during pass B + cell, NOT on the vmcnt(0) drain (v12 issued
//      it right before the drain -> +1us/round on the serial chain).
//  (b) L1: fence hx only -> pass A runs while hh loads fly -> fence hh -> pass B.
// Invariant (v11 lesson): NO load issued near the drain; ALL loads at round start
// or mid-compute. All h/flag traffic relaxed AGENT (SC1) - proven protocol.
__global__ __launch_bounds__(256, 1) void k_rec2(
    const u16* __restrict__ Wihb,      // bf16 [2][2048][512]
    const u16* __restrict__ Whhb,      // bf16 [2][2048][512]
    const u16* __restrict__ Xbuf,      // bf16 [MTOT][512] = relu(feat@Win+bin)
    const float* __restrict__ bih, const float* __restrict__ bhh,  // [2][2048]
    u64* __restrict__ h0r,             // [4][256][128] u64 ring (h0, bf16, pre-relu)
    u64* __restrict__ h1A, u64* __restrict__ h1B,
    int* __restrict__ bar)
{
    extern __shared__ u16 smem[];      // 131072 B: sWih [64*512] | sWhh [64*512]
    int tid = threadIdx.x;
    int w = tid >> 6, lane = tid & 63, q = lane >> 4, r = lane & 15;
    int lay  = blockIdx.x >> 7;
    int bid7 = blockIdx.x & 127;
    int mg = bid7 & 3, jb = bid7 >> 2;
    int m0 = mg*64, j0 = jb*16;
    int j = j0 + r;
    int* F0x = bar;
    int* F1x = bar + 2048;
    int fidx = (mg*GRPB + jb)*FS;
    const u16* sWih = smem;
    const u16* sWhh = smem + 64*512;

    {   // stage Wih + Whh slices for my layer, XOR-swizzled
        int row = tid >> 2, seg = tid & 3;
        int g = row >> 4, jj = row & 15;
        const u16* srcI = Wihb + (size_t)lay*G4*HH + (size_t)(g*HH + j0 + jj)*HH;
        const u16* srcW = Whhb + (size_t)lay*G4*HH + (size_t)(g*HH + j0 + jj)*HH;
        for (int i = 0; i < 16; i++){
            int c = seg*16 + i;
            *(uint4*)(&smem[row*512 + ((c ^ (row & 7)) * 8)]) = *(const uint4*)(srcI + c*8);
            *(uint4*)(&smem[64*512 + row*512 + ((c ^ (row & 7)) * 8)]) = *(const uint4*)(srcW + c*8);
        }
    }
    float creg[4] = {0.f, 0.f, 0.f, 0.f};
    // zero my t=0 h-source: L0 -> ring slot 3 (= h0(-1)); L1 -> h1A (= h1(-1))
    if ((r & 3) == 0){
        u64* hz = lay ? h1A : (h0r + (size_t)3*BB*(HH/4));
        for (int reg = 0; reg < 4; reg++){
            int m = m0 + w*16 + q*4 + reg;
            __hip_atomic_store(&hz[(size_t)m*(HH/4) + ((j0 + r) >> 2)], 0ULL,
                               __ATOMIC_RELAXED, __HIP_MEMORY_SCOPE_AGENT);
        }
    }
    asm volatile("s_waitcnt vmcnt(0)" ::: "memory");
    __syncthreads();   // prologue stores drained; weights staged
    if (tid == 0)
        __hip_atomic_store(lay ? &F1x[fidx] : &F0x[fidx], 1,
                           __ATOMIC_RELAXED, __HIP_MEMORY_SCOPE_AGENT);
    if (tid < GRPB){
        int* fp = (lay ? F1x : F0x) + (mg*GRPB + tid)*FS;
        long long t0c = clock64();
        while (__hip_atomic_load(fp, __ATOMIC_RELAXED, __HIP_MEMORY_SCOPE_AGENT) < 1){
            __builtin_amdgcn_s_sleep(1);
            if (clock64() - t0c > 50000000LL) break;
        }
    }
    __syncthreads();

    float bs[4];
    for (int g = 0; g < 4; g++)
        bs[g] = bih[lay*G4 + g*HH + j] + bhh[lay*G4 + g*HH + j];

    if (!lay){
        // ======================= LAYER 0 =======================
        const u64* xb = (const u64*)Xbuf;
        u64 xn[32];
        {   // prefetch x(0)
            const u64* xrow = xb + ((size_t)(m0 + w*16 + r)*TT + 0)*(HH/4);
            #pragma unroll
            for (int kc = 0; kc < 16; kc++){
                int jg0 = kc*8 + q*2;
                xn[kc*2]   = __builtin_nontemporal_load(&xrow[jg0]);
                xn[kc*2+1] = __builtin_nontemporal_load(&xrow[jg0+1]);
            }
        }

        for (int t = 0; t < TT; t++){
            const u64* hsrc = h0r + (size_t)((t + 3) & 3)*BB*(HH/4);   // h0(t-1)
            u32* hdst32 = (u32*)(h0r + (size_t)(t & 3)*BB*(HH/4));     // h0(t)
            const u64* hrow = hsrc + (size_t)(m0 + w*16 + r)*(HH/4);

            // issue hd loads FIRST; they fly under pass A (which uses only xn regs)
            u64 hd[32];
            #pragma unroll
            for (int kc = 0; kc < 16; kc++){
                int jg0 = kc*8 + q*2;
                hd[kc*2]   = __hip_atomic_load(&hrow[jg0],   __ATOMIC_RELAXED, __HIP_MEMORY_SCOPE_AGENT);
                hd[kc*2+1] = __hip_atomic_load(&hrow[jg0+1], __ATOMIC_RELAXED, __HIP_MEMORY_SCOPE_AGENT);
            }

            f32x4 acc[4];
            for (int g = 0; g < 4; g++){
                acc[g][0] = 0.f; acc[g][1] = 0.f; acc[g][2] = 0.f; acc[g][3] = 0.f;
            }
            // pass A: Wih0 @ x(t)  (x prefetched last round; hd loads in flight)
            #pragma unroll
            for (int kc = 0; kc < 16; kc++){
                union { u64 d[2]; bf16x8 v; } au;
                au.d[0] = xn[kc*2];
                au.d[1] = xn[kc*2+1];
                int cbase = kc*4 + q;
                #pragma unroll
                for (int g = 0; g < 4; g++){
                    int row = g*16 + r;
                    bf16x8 b = *(const bf16x8*)(&sWih[row*512 + ((cbase ^ (row & 7)) * 8)]);
                    acc[g] = __builtin_amdgcn_mfma_f32_16x16x32_bf16(au.v, b, acc[g], 0, 0, 0);
                }
            }
            // hd must be materialized now (keep-alive fence) for pass B
            asm volatile("" :
                "+v"(hd[0]),  "+v"(hd[1]),  "+v"(hd[2]),  "+v"(hd[3]),
                "+v"(hd[4]),  "+v"(hd[5]),  "+v"(hd[6]),  "+v"(hd[7]),
                "+v"(hd[8]),  "+v"(hd[9]),  "+v"(hd[10]), "+v"(hd[11]),
                "+v"(hd[12]), "+v"(hd[13]), "+v"(hd[14]), "+v"(hd[15]));
            asm volatile("" :
                "+v"(hd[16]), "+v"(hd[17]), "+v"(hd[18]), "+v"(hd[19]),
                "+v"(hd[20]), "+v"(hd[21]), "+v"(hd[22]), "+v"(hd[23]),
                "+v"(hd[24]), "+v"(hd[25]), "+v"(hd[26]), "+v"(hd[27]),
                "+v"(hd[28]), "+v"(hd[29]), "+v"(hd[30]), "+v"(hd[31]));
            __builtin_amdgcn_sched_barrier(0);
            // prefetch x(t+1): completes during pass B + cell, NOT on the drain
            if (t + 1 < TT){
                const u64* xrow = xb + ((size_t)(m0 + w*16 + r)*TT + (t+1))*(HH/4);
                #pragma unroll
                for (int kc = 0; kc < 16; kc++){
                    int jg0 = kc*8 + q*2;
                    xn[kc*2]   = __builtin_nontemporal_load(&xrow[jg0]);
                    xn[kc*2+1] = __builtin_nontemporal_load(&xrow[jg0+1]);
                }
            }
            // pass B: Whh0 @ h0(t-1)
            #pragma unroll
            for (int kc = 0; kc < 16; kc++){
                union { u64 d[2]; bf16x8 v; } au;
                au.d[0] = hd[kc*2];
                au.d[1] = hd[kc*2+1];
                int cbase = kc*4 + q;
                #pragma unroll
                for (int g = 0; g < 4; g++){
                    int row = g*16 + r;
                    bf16x8 b = *(const bf16x8*)(&sWhh[row*512 + ((cbase ^ (row & 7)) * 8)]);
                    acc[g] = __builtin_amdgcn_mfma_f32_16x16x32_bf16(au.v, b, acc[g], 0, 0, 0);
                }
            }

            #pragma unroll
            for (int reg = 0; reg < 4; reg++){
                int m = m0 + w*16 + q*4 + reg;
                float Gi = acc[0][reg] + bs[0];
                float Gf = acc[1][reg] + bs[1];
                float Gg = acc[2][reg] + bs[2];
                float Go = acc[3][reg] + bs[3];
                float iv = 1.f/(1.f + __expf(-Gi));
                float fv = 1.f/(1.f + __expf(-Gf));
                float gv = fast_tanh(Gg);
                float ov = 1.f/(1.f + __expf(-Go));
                float c = fv * creg[reg] + iv * gv;
                creg[reg] = c;
                float h = ov * fast_tanh(c);
                u32 own = (u32)f2bf(h);
                u32 p01 = own | (((u32)__shfl_xor((int)own, 1)) << 16);
                if ((r & 1) == 0){
                    __hip_atomic_store(&hdst32[(size_t)m*(HH/2) + ((j0 + r) >> 1)], p01,
                                       __ATOMIC_RELAXED, __HIP_MEMORY_SCOPE_AGENT);
                }
            }

            asm volatile("s_waitcnt vmcnt(0)" ::: "memory");
            __syncthreads();
            if (tid == 0)
                __hip_atomic_store(&F0x[fidx], t + 2, __ATOMIC_RELAXED, __HIP_MEMORY_SCOPE_AGENT);
            if (t + 1 < TT){
                if (tid < 64){
                    long long t0c = clock64();
                    const int* fp; int thr;
                    if (lane < GRPB){ fp = &F0x[(mg*GRPB + lane)*FS];        thr = t + 2; }  // peers
                    else            { fp = &F1x[(mg*GRPB + (lane-GRPB))*FS]; thr = t - 1; }  // ring slack
                    while (__hip_atomic_load(fp, __ATOMIC_RELAXED, __HIP_MEMORY_SCOPE_AGENT) < thr){
                        __builtin_amdgcn_s_sleep(1);
                        if (clock64() - t0c > 50000000LL) break;
                    }
                }
                __syncthreads();
            }
        }
    } else {
        // ======================= LAYER 1 =======================
        // wait h0(0) visible (L0 round 0 done)
        if (tid < GRPB){
            const int* fp = &F0x[(mg*GRPB + tid)*FS];
            long long t0c = clock64();
            while (__hip_atomic_load(fp, __ATOMIC_RELAXED, __HIP_MEMORY_SCOPE_AGENT) < 2){
                __builtin_amdgcn_s_sleep(1);
                if (clock64() - t0c > 50000000LL) break;
            }
        }
        __syncthreads();

        for (int t = 0; t < TT; t++){
            const u64* xsrc = h0r + (size_t)(t & 3)*BB*(HH/4);   // h0(t), pre-relu
            const u64* hsrc = (t & 1) ? h1B : h1A;               // h1(t-1); t=0 -> zeros
            u64*       hdst = (t & 1) ? h1A : h1B;               // t=99 -> h1A
            const u64* xrow = xsrc + (size_t)(m0 + w*16 + r)*(HH/4);
            const u64* hrow = hsrc + (size_t)(m0 + w*16 + r)*(HH/4);

            // issue hx then hh back-to-back (one window); fence ONLY hx before
            // pass A so hh keeps flying under it
            u64 hx[32], hh[32];
            #pragma unroll
            for (int kc = 0; kc < 16; kc++){
                int jg0 = kc*8 + q*2;
                hx[kc*2]   = __hip_atomic_load(&xrow[jg0],   __ATOMIC_RELAXED, __HIP_MEMORY_SCOPE_AGENT);
                hx[kc*2+1] = __hip_atomic_load(&xrow[jg0+1], __ATOMIC_RELAXED, __HIP_MEMORY_SCOPE_AGENT);
            }
            #pragma unroll
            for (int kc = 0; kc < 16; kc++){
                int jg0 = kc*8 + q*2;
                hh[kc*2]   = __hip_atomic_load(&hrow[jg0],   __ATOMIC_RELAXED, __HIP_MEMORY_SCOPE_AGENT);
                hh[kc*2+1] = __hip_atomic_load(&hrow[jg0+1], __ATOMIC_RELAXED, __HIP_MEMORY_SCOPE_AGENT);
            }
            asm volatile("" :
                "+v"(hx[0]),  "+v"(hx[1]),  "+v"(hx[2]),  "+v"(hx[3]),
                "+v"(hx[4]),  "+v"(hx[5]),  "+v"(hx[6]),  "+v"(hx[7]),
                "+v"(hx[8]),  "+v"(hx[9]),  "+v"(hx[10]), "+v"(hx[11]),
                "+v"(hx[12]), "+v"(hx[13]), "+v"(hx[14]), "+v"(hx[15]));
            asm volatile("" :
                "+v"(hx[16]), "+v"(hx[17]), "+v"(hx[18]), "+v"(hx[19]),
                "+v"(hx[20]), "+v"(hx[21]), "+v"(hx[22]), "+v"(hx[23]),
                "+v"(hx[24]), "+v"(hx[25]), "+v"(hx[26]), "+v"(hx[27]),
                "+v"(hx[28]), "+v"(hx[29]), "+v"(hx[30]), "+v"(hx[31]));
            __builtin_amdgcn_sched_barrier(0);
            // relu in-register (exact)
            #pragma unroll
            for (int i = 0; i < 32; i++) hx[i] = relu4_bf16(hx[i]);

            f32x4 acc[4];
            for (int g = 0; g < 4; g++){
                acc[g][0] = 0.f; acc[g][1] = 0.f; acc[g][2] = 0.f; acc[g][3] = 0.f;
            }
            // pass A: Wih1 @ relu(h0(t))   (hh loads in flight underneath)
            #pragma unroll
            for (int kc = 0; kc < 16; kc++){
                union { u64 d[2]; bf16x8 v; } au;
                au.d[0] = hx[kc*2];
                au.d[1] = hx[kc*2+1];
                int cbase = kc*4 + q;
                #pragma unroll
                for (int g = 0; g < 4; g++){
                    int row = g*16 + r;
                    bf16x8 b = *(const bf16x8*)(&sWih[row*512 + ((cbase ^ (row & 7)) * 8)]);
                    acc[g] = __builtin_amdgcn_mfma_f32_16x16x32_bf16(au.v, b, acc[g], 0, 0, 0);
                }
            }
            asm volatile("" :
                "+v"(hh[0]),  "+v"(hh[1]),  "+v"(hh[2]),  "+v"(hh[3]),
                "+v"(hh[4]),  "+v"(hh[5]),  "+v"(hh[6]),  "+v"(hh[7]),
                "+v"(hh[8]),  "+v"(hh[9]),  "+v"(hh[10]), "+v"(hh[11]),
                "+v"(hh[12]), "+v"(hh[13]), "+v"(hh[14]), "+v"(hh[15]));
            asm volatile("" :
                "+v"(hh[16]), "+v"(hh[17]), "+v"(hh[18]), "+v"(hh[19]),
                "+v"(hh[20]), "+v"(hh[21]), "+v"(hh[22]), "+v"(hh[23]),
                "+v"(hh[24]), "+v"(hh[25]), "+v"(hh[26]), "+v"(hh[27]),
                "+v"(hh[28]), "+v"(hh[29]), "+v"(hh[30]), "+v"(hh[31]));
            __builtin_amdgcn_sched_barrier(0);
            // pass B: Whh1 @ h1(t-1)
            #pragma unroll
            for (int kc = 0; kc < 16; kc++){
                union { u64 d[2]; bf16x8 v; } au;
                au.d[0] = hh[kc*2];
                au.d[1] = hh[kc*2+1];
                int cbase = kc*4 + q;
                #pragma unroll
                for (int g = 0; g < 4; g++){
                    int row = g*16 + r;
                    bf16x8 b = *(const bf16x8*)(&sWhh[row*512 + ((cbase ^ (row & 7)) * 8)]);
                    acc[g] = __builtin_amdgcn_mfma_f32_16x16x32_bf16(au.v, b, acc[g], 0, 0, 0);
                }
            }

            u32* hdst32 = (u32*)hdst;
            #pragma unroll
            for (int reg = 0; reg < 4; reg++){
                int m = m0 + w*16 + q*4 + reg;
                float Gi = acc[0][reg] + bs[0];
                float Gf = acc[1][reg] + bs[1];
                float Gg = acc[2][reg] + bs[2];
                float Go = acc[3][reg] + bs[3];
                float iv = 1.f/(1.f + __expf(-Gi));
                float fv = 1.f/(1.f + __expf(-Gf));
                float gv = fast_tanh(Gg);
                float ov = 1.f/(1.f + __expf(-Go));
                float c = fv * creg[reg] + iv * gv;
                creg[reg] = c;
                float h = ov * fast_tanh(c);
                u32 own = (u32)f2bf(h);
                u32 p01 = own | (((u32)__shfl_xor((int)own, 1)) << 16);
                if ((r & 1) == 0){
                    __hip_atomic_store(&hdst32[(size_t)m*(HH/2) + ((j0 + r) >> 1)], p01,
                                       __ATOMIC_RELAXED, __HIP_MEMORY_SCOPE_AGENT);
                }
            }

            asm volatile("s_waitcnt vmcnt(0)" ::: "memory");
            __syncthreads();
            if (tid == 0)
                __hip_atomic_store(&F1x[fidx], t + 2, __ATOMIC_RELAXED, __HIP_MEMORY_SCOPE_AGENT);

            if (t + 1 < TT){
                if (tid < 64){
                    long long t0c = clock64();
                    const int* fp; int thr;
                    if (lane < GRPB){ fp = &F1x[(mg*GRPB + lane)*FS];        thr = t + 2; }  // peers: h1(t)
                    else            { fp = &F0x[(mg*GRPB + (lane-GRPB))*FS]; thr = t + 3; }  // h0(t+1)
                    while (__hip_atomic_load(fp, __ATOMIC_RELAXED, __HIP_MEMORY_SCOPE_AGENT) < thr){
                        __builtin_amdgcn_s_sleep(1);
                        if (clock64() - t0c > 50000000LL) break;
                    }
                }
                __syncthreads();
            }
        }
    }
}

// ---- heads: fp32 output (d_out is float*), zero-sentinel kept ----
__global__ void k_heads(
    const u16* __restrict__ hfin, const float* __restrict__ Wout,
    const float* __restrict__ bout, const float* __restrict__ Wcls,
    const float* __restrict__ bcls, float* __restrict__ out)
{
    __shared__ float last[HH];
    int b = blockIdx.x, tid = threadIdx.x;
    for (int h = tid; h < HH; h += 256) last[h] = fmaxf(bf2f(hfin[b*HH + h]), 0.f);
    __syncthreads();
    for (int o = tid; o < NCONT + NCAT*VV; o += 256){
        if (o < NCONT){
            float a = bout[o];
            for (int h = 0; h < HH; h++) a += last[h] * Wout[h*NCONT + o];
            out[b*NCONT + o] = (a == 0.0f) ? 7.0f : a;
        } else {
            int oc = o - NCONT;
            int n = oc >> 5, v = oc & 31;
            float a = bcls[oc];
            const float* wp = Wcls + (size_t)n*HH*VV + v;
            for (int h = 0; h < HH; h++) a += last[h] * wp[h*VV];
            out[BB*NCONT + b*(NCAT*VV) + oc] = (a == 0.0f) ? 7.0f : a;
        }
    }
}

extern "C" void kernel_launch(void* const* d_in, const int* in_sizes, int n_in,
                              void* d_out, int out_size, void* d_ws, size_t ws_size,
                              hipStream_t stream){
    const float* x      = (const float*)d_in[0];
    const float* smean  = (const float*)d_in[1];
    const float* sscale = (const float*)d_in[2];
    const float* emb    = (const float*)d_in[3];
    const float* Win    = (const float*)d_in[4];
    const float* bin    = (const float*)d_in[5];
    const float* Wih    = (const float*)d_in[6];
    const float* Whh    = (const float*)d_in[7];
    const float* bih    = (const float*)d_in[8];
    const float* bhh    = (const float*)d_in[9];
    const float* Wout   = (const float*)d_in[10];
    const float* bout   = (const float*)d_in[11];
    const float* Wcls   = (const float*)d_in[12];
    const float* bcls   = (const float*)d_in[13];
    (void)in_sizes; (void)n_in; (void)out_size;

    char* ws = (char*)d_ws;
    size_t off = 0;
    u16*      feat  = (u16*)(ws + off);      off += (size_t)MTOT*KIN*2;   //   9.8 MB
    u16*      WinTb = (u16*)(ws + off);      off += (size_t)HH*KIN*2;     //   0.2 MB
    u16*      Xbuf  = (u16*)(ws + off);      off += (size_t)MTOT*HH*2;    //  26.2 MB
    u16*      Wihb  = (u16*)(ws + off);      off += (size_t)2*G4*HH*2;    //   4.2 MB
    u16*      Whhb  = (u16*)(ws + off);      off += (size_t)2*G4*HH*2;    //   4.2 MB
    u64*      h0r   = (u64*)(ws + off);      off += (size_t)4*BB*HH*2;    //   1.0 MB
    u64*      h1A   = (u64*)(ws + off);      off += (size_t)BB*HH*2;
    u64*      h1B   = (u64*)(ws + off);      off += (size_t)BB*HH*2;
    int*      bar   = (int*)(ws + off);      off += 4096*4;               //  16 KB
    (void)off; (void)ws_size;

    // fused weight prep: WinT + Wih cvt + Whh cvt in ONE dispatch
    int prep_n = HH*KIN + 2*2*G4*HH;
    PredictionModel_58841051955204_kernel<<<(prep_n + 255)/256, 256, 0, stream>>>(
        Win, WinTb, Wih, Wihb, Whh, Whhb);

    // featurize (+ bar zeroing in block 0)
    k_feat<<<1600, 256, 0, stream>>>(x, smean, sscale, emb, feat, bar);
    // Xbuf = relu(feat @ W_in + b_in) (bf16) — the only pre-GEMM left
    k_gemm<<<dim3(400, 2), 256, 0, stream>>>(feat, KIN, WinTb, KIN, bin, (const float*)0,
                                             Xbuf, HH, 6, 1, 0);
    // fused both-layer recurrence; L0 streams x from Xbuf
    k_rec2<<<256, 256, 131072, stream>>>(Wihb, Whhb, Xbuf, bih, bhh,
                                         h0r, h1A, h1B, bar);
    // T=100 even: layer-1 t=99 (odd) stores to h1A; heads write fp32 d_out
    k_heads<<<256, 256, 0, stream>>>((const u16*)h1A, Wout, bout, Wcls, bcls, (float*)d_out);
}

// Round 14
// 1269.240 us; speedup vs baseline: 1.2095x; 1.0188x over previous
//
#include <hip/hip_runtime.h>

#define BB 256
#define TT 100
#define HH 512
#define G4 2048
#define INL 176
#define KIN 192
#define NCAT 16
#define NCONT 48
#define VV 32
#define EE 8
#define MTOT (BB*TT)
#define GRPB 32   // j-blocks per m-group
#define FS 16     // flag stride in ints (64B)

typedef unsigned short u16;
typedef unsigned int   u32;
typedef unsigned long long u64;
typedef __attribute__((ext_vector_type(8))) short bf16x8;
typedef __attribute__((ext_vector_type(4))) float f32x4;

__device__ __forceinline__ float bf2f(u16 u){
    union { u32 i; float f; } v; v.i = ((u32)u) << 16; return v.f;
}
__device__ __forceinline__ u16 f2bf(float f){
    union { float f; u32 i; } v; v.f = f;
    u32 b = v.i;
    b += 0x7FFFu + ((b >> 16) & 1u);   // round-to-nearest-even
    return (u16)(b >> 16);
}
// exact identity tanh(x) = 1 - 2/(e^{2x}+1); __expf precision << bf16 rounding
__device__ __forceinline__ float fast_tanh(float x){
    float e = __expf(2.f * x);
    return 1.f - 2.f / (e + 1.f);
}
// packed relu on 4 bf16 halves: zero any half with sign bit set (exact)
__device__ __forceinline__ u64 relu4_bf16(u64 v){
    u64 s = v & 0x8000800080008000ULL;
    u64 m = s - (s >> 15);            // 0x7FFF per negative half (no cross-half borrow)
    return v & ~(s | m);
}
// thinned-watchdog SC1 flag poll: clock64 only every 32 iterations
__device__ __forceinline__ void poll_flag(const int* fp, int thr){
    int it = 0;
    long long t0c = clock64();
    while (__hip_atomic_load(fp, __ATOMIC_RELAXED, __HIP_MEMORY_SCOPE_AGENT) < thr){
        __builtin_amdgcn_s_sleep(1);
        if (((++it) & 31) == 0 && clock64() - t0c > 50000000LL) break;  // degrade, not hang
    }
}

#define FENCE32(a) \
    asm volatile("" : \
        "+v"(a[0]),  "+v"(a[1]),  "+v"(a[2]),  "+v"(a[3]), \
        "+v"(a[4]),  "+v"(a[5]),  "+v"(a[6]),  "+v"(a[7]), \
        "+v"(a[8]),  "+v"(a[9]),  "+v"(a[10]), "+v"(a[11]), \
        "+v"(a[12]), "+v"(a[13]), "+v"(a[14]), "+v"(a[15])); \
    asm volatile("" : \
        "+v"(a[16]), "+v"(a[17]), "+v"(a[18]), "+v"(a[19]), \
        "+v"(a[20]), "+v"(a[21]), "+v"(a[22]), "+v"(a[23]), \
        "+v"(a[24]), "+v"(a[25]), "+v"(a[26]), "+v"(a[27]), \
        "+v"(a[28]), "+v"(a[29]), "+v"(a[30]), "+v"(a[31])); \
    __builtin_amdgcn_sched_barrier(0)

// ---- canonical-name kernel: fused weight prep ----
__global__ void PredictionModel_58841051955204_kernel(
    const float* __restrict__ Win, u16* __restrict__ WinT,
    const float* __restrict__ Wih, u16* __restrict__ Wihb,
    const float* __restrict__ Whh, u16* __restrict__ Whhb){
    int idx = blockIdx.x*256 + threadIdx.x;
    if (idx < HH*KIN){
        int h = idx / KIN, i = idx % KIN;
        WinT[idx] = (i < INL) ? f2bf(Win[i*HH + h]) : (u16)0;
        return;
    }
    int c1 = idx - HH*KIN;
    if (c1 < 2*G4*HH){ Wihb[c1] = f2bf(Wih[c1]); return; }
    int c2 = c1 - 2*G4*HH;
    if (c2 < 2*G4*HH) Whhb[c2] = f2bf(Whh[c2]);
}

// ---- featurize: fp32 inputs -> bf16 feat [25600][192]; block 0 also zeros bar ----
__global__ void k_feat(const float* __restrict__ x, const float* __restrict__ mean,
                       const float* __restrict__ scale, const float* __restrict__ emb,
                       u16* __restrict__ feat, int* __restrict__ bar){
    if (blockIdx.x == 0){
        for (int i = threadIdx.x; i < 4096; i += 256)
            __hip_atomic_store(&bar[i], 0, __ATOMIC_RELAXED, __HIP_MEMORY_SCOPE_AGENT);
    }
    int idx = blockIdx.x*256 + threadIdx.x;
    int bt = idx >> 4, g = idx & 15;
    if (bt >= MTOT) return;
    const float* xr = x + (size_t)bt*64;
    u16* fr = feat + (size_t)bt*KIN;
    int k0 = g*4;
    int ci = (int)xr[k0];
    if (ci < 0) ci = 0;
    if (ci > VV-1) ci = VV-1;
    const float* ep = emb + (size_t)(g*VV + ci)*EE;
    int c0 = g*11;
    for (int e = 0; e < 8; e++) fr[c0+e] = f2bf(ep[e]);
    for (int j = 1; j <= 3; j++){
        int k = k0 + j;
        fr[c0 + 8 + (j-1)] = f2bf((xr[k] - mean[k]) / scale[k]);
    }
    fr[INL + g] = 0;
}

// ---- MFMA GEMM: out[m,n] = act(A(bf16) @ W(bf16 [N][K])^T + b1 + b2) ----
__global__ __launch_bounds__(256) void k_gemm(
    const u16* __restrict__ A, int lda,
    const u16* __restrict__ W, int K,
    const float* __restrict__ bias1, const float* __restrict__ bias2,
    void* __restrict__ out, int ldo, int kc_cnt, int do_relu, int out_half)
{
    __shared__ u16 sA[64*40];
    __shared__ u16 sB[256*40];
    int tid = threadIdx.x;
    int w = tid >> 6, lane = tid & 63, q = lane >> 4, r = lane & 15;
    int m0 = blockIdx.x * 64;
    int n0 = blockIdx.y * 256;

    f32x4 acc[4][4];
    for (int a_ = 0; a_ < 4; a_++)
        for (int b_ = 0; b_ < 4; b_++){
            acc[a_][b_][0] = 0.f; acc[a_][b_][1] = 0.f;
            acc[a_][b_][2] = 0.f; acc[a_][b_][3] = 0.f;
        }

    for (int kc = 0; kc < kc_cnt; kc++){
        {
            int row = tid >> 2, seg = tid & 3;
            uint4 v = *(const uint4*)(A + (size_t)(m0+row)*lda + kc*32 + seg*8);
            *(uint4*)(&sA[row*40 + seg*8]) = v;
            const u16* wr = W + (size_t)(n0 + tid)*K + kc*32;
            uint4 b0 = *(const uint4*)(wr);
            uint4 b1 = *(const uint4*)(wr+8);
            uint4 b2 = *(const uint4*)(wr+16);
            uint4 b3 = *(const uint4*)(wr+24);
            u16* d = &sB[tid*40];
            *(uint4*)(d)    = b0; *(uint4*)(d+8)  = b1;
            *(uint4*)(d+16) = b2; *(uint4*)(d+24) = b3;
        }
        __syncthreads();
        bf16x8 a[4], b[4];
        for (int mt = 0; mt < 4; mt++) a[mt] = *(const bf16x8*)(&sA[(mt*16 + r)*40 + q*8]);
        for (int i = 0; i < 4; i++)    b[i]  = *(const bf16x8*)(&sB[((w*4+i)*16 + r)*40 + q*8]);
        for (int mt = 0; mt < 4; mt++)
            for (int i = 0; i < 4; i++)
                acc[mt][i] = __builtin_amdgcn_mfma_f32_16x16x32_bf16(a[mt], b[i], acc[mt][i], 0, 0, 0);
        __syncthreads();
    }

    for (int i = 0; i < 4; i++){
        int n = n0 + (w*4+i)*16 + r;
        float bs = 0.f;
        if (bias1) bs += bias1[n];
        if (bias2) bs += bias2[n];
        for (int mt = 0; mt < 4; mt++){
            for (int reg = 0; reg < 4; reg++){
                int m = m0 + mt*16 + q*4 + reg;
                float v = acc[mt][i][reg] + bs;
                if (do_relu) v = fmaxf(v, 0.f);
                if (out_half) ((_Float16*)out)[(size_t)m*ldo + n] = (_Float16)v;
                else          ((u16*)out)[(size_t)m*ldo + n] = f2bf(v);
            }
        }
    }
}

// ---- FUSED two-layer recurrence v14 ----
// vs v13 (k_rec2 1158us): L0's serial chain emptied into the poll window.
//  L0 steady round: fence hd -> pass B -> cell -> drain/flag -> [issue x(t+1),
//  poll, sync, issue hd(t), fence x, pass A(t+1)] -> loop. Pass A and the x-issue
//  run UNDER the poll/flight window; hd flight is covered by pass A. Chain is just
//  pass B + cell + drain + flag + poll.
//  All polls: thinned watchdog (clock64 every 32 iters, not every iter).
// L1 unchanged (both operands flag-gated; nothing hoistable).
__global__ __launch_bounds__(256, 1) void k_rec2(
    const u16* __restrict__ Wihb,      // bf16 [2][2048][512]
    const u16* __restrict__ Whhb,      // bf16 [2][2048][512]
    const u16* __restrict__ Xbuf,      // bf16 [MTOT][512] = relu(feat@Win+bin)
    const float* __restrict__ bih, const float* __restrict__ bhh,  // [2][2048]
    u64* __restrict__ h0r,             // [4][256][128] u64 ring (h0, bf16, pre-relu)
    u64* __restrict__ h1A, u64* __restrict__ h1B,
    int* __restrict__ bar)
{
    extern __shared__ u16 smem[];      // 131072 B: sWih [64*512] | sWhh [64*512]
    int tid = threadIdx.x;
    int w = tid >> 6, lane = tid & 63, q = lane >> 4, r = lane & 15;
    int lay  = blockIdx.x >> 7;
    int bid7 = blockIdx.x & 127;
    int mg = bid7 & 3, jb = bid7 >> 2;
    int m0 = mg*64, j0 = jb*16;
    int j = j0 + r;
    int* F0x = bar;
    int* F1x = bar + 2048;
    int fidx = (mg*GRPB + jb)*FS;
    const u16* sWih = smem;
    const u16* sWhh = smem + 64*512;

    {   // stage Wih + Whh slices for my layer, XOR-swizzled
        int row = tid >> 2, seg = tid & 3;
        int g = row >> 4, jj = row & 15;
        const u16* srcI = Wihb + (size_t)lay*G4*HH + (size_t)(g*HH + j0 + jj)*HH;
        const u16* srcW = Whhb + (size_t)lay*G4*HH + (size_t)(g*HH + j0 + jj)*HH;
        for (int i = 0; i < 16; i++){
            int c = seg*16 + i;
            *(uint4*)(&smem[row*512 + ((c ^ (row & 7)) * 8)]) = *(const uint4*)(srcI + c*8);
            *(uint4*)(&smem[64*512 + row*512 + ((c ^ (row & 7)) * 8)]) = *(const uint4*)(srcW + c*8);
        }
    }
    float creg[4] = {0.f, 0.f, 0.f, 0.f};
    // zero my t=0 h-source: L0 -> ring slot 3 (= h0(-1)); L1 -> h1A (= h1(-1))
    if ((r & 3) == 0){
        u64* hz = lay ? h1A : (h0r + (size_t)3*BB*(HH/4));
        for (int reg = 0; reg < 4; reg++){
            int m = m0 + w*16 + q*4 + reg;
            __hip_atomic_store(&hz[(size_t)m*(HH/4) + ((j0 + r) >> 2)], 0ULL,
                               __ATOMIC_RELAXED, __HIP_MEMORY_SCOPE_AGENT);
        }
    }
    asm volatile("s_waitcnt vmcnt(0)" ::: "memory");
    __syncthreads();   // prologue stores drained; weights staged
    if (tid == 0)
        __hip_atomic_store(lay ? &F1x[fidx] : &F0x[fidx], 1,
                           __ATOMIC_RELAXED, __HIP_MEMORY_SCOPE_AGENT);
    if (tid < GRPB)
        poll_flag((lay ? F1x : F0x) + (mg*GRPB + tid)*FS, 1);
    __syncthreads();

    float bs[4];
    for (int g = 0; g < 4; g++)
        bs[g] = bih[lay*G4 + g*HH + j] + bhh[lay*G4 + g*HH + j];

    if (!lay){
        // ======================= LAYER 0 =======================
        const u64* xb = (const u64*)Xbuf;
        u64 xn[32], hd[32];
        // issue hd(-1) loads (ring slot 3, zeros — visible per initial flag round)
        {
            const u64* hrow = h0r + (size_t)3*BB*(HH/4) + (size_t)(m0 + w*16 + r)*(HH/4);
            #pragma unroll
            for (int kc = 0; kc < 16; kc++){
                int jg0 = kc*8 + q*2;
                hd[kc*2]   = __hip_atomic_load(&hrow[jg0],   __ATOMIC_RELAXED, __HIP_MEMORY_SCOPE_AGENT);
                hd[kc*2+1] = __hip_atomic_load(&hrow[jg0+1], __ATOMIC_RELAXED, __HIP_MEMORY_SCOPE_AGENT);
            }
        }
        // load x(0); fence; accA = Wih0 @ x(0)
        {
            const u64* xrow = xb + ((size_t)(m0 + w*16 + r)*TT + 0)*(HH/4);
            #pragma unroll
            for (int kc = 0; kc < 16; kc++){
                int jg0 = kc*8 + q*2;
                xn[kc*2]   = __builtin_nontemporal_load(&xrow[jg0]);
                xn[kc*2+1] = __builtin_nontemporal_load(&xrow[jg0+1]);
            }
        }
        FENCE32(xn);
        f32x4 accA[4];
        for (int g = 0; g < 4; g++){
            accA[g][0] = 0.f; accA[g][1] = 0.f; accA[g][2] = 0.f; accA[g][3] = 0.f;
        }
        #pragma unroll
        for (int kc = 0; kc < 16; kc++){
            union { u64 d[2]; bf16x8 v; } au;
            au.d[0] = xn[kc*2];
            au.d[1] = xn[kc*2+1];
            int cbase = kc*4 + q;
            #pragma unroll
            for (int g = 0; g < 4; g++){
                int row = g*16 + r;
                bf16x8 b = *(const bf16x8*)(&sWih[row*512 + ((cbase ^ (row & 7)) * 8)]);
                accA[g] = __builtin_amdgcn_mfma_f32_16x16x32_bf16(au.v, b, accA[g], 0, 0, 0);
            }
        }

        for (int t = 0; t < TT; t++){
            u32* hdst32 = (u32*)(h0r + (size_t)(t & 3)*BB*(HH/4));     // h0(t)

            // steady-state serial chain: fence hd -> pass B -> cell -> drain/flag
            FENCE32(hd);
            f32x4 acc[4];
            for (int g = 0; g < 4; g++) acc[g] = accA[g];
            #pragma unroll
            for (int kc = 0; kc < 16; kc++){
                union { u64 d[2]; bf16x8 v; } au;
                au.d[0] = hd[kc*2];
                au.d[1] = hd[kc*2+1];
                int cbase = kc*4 + q;
                #pragma unroll
                for (int g = 0; g < 4; g++){
                    int row = g*16 + r;
                    bf16x8 b = *(const bf16x8*)(&sWhh[row*512 + ((cbase ^ (row & 7)) * 8)]);
                    acc[g] = __builtin_amdgcn_mfma_f32_16x16x32_bf16(au.v, b, acc[g], 0, 0, 0);
                }
            }

            #pragma unroll
            for (int reg = 0; reg < 4; reg++){
                int m = m0 + w*16 + q*4 + reg;
                float Gi = acc[0][reg] + bs[0];
                float Gf = acc[1][reg] + bs[1];
                float Gg = acc[2][reg] + bs[2];
                float Go = acc[3][reg] + bs[3];
                float iv = 1.f/(1.f + __expf(-Gi));
                float fv = 1.f/(1.f + __expf(-Gf));
                float gv = fast_tanh(Gg);
                float ov = 1.f/(1.f + __expf(-Go));
                float c = fv * creg[reg] + iv * gv;
                creg[reg] = c;
                float h = ov * fast_tanh(c);
                u32 own = (u32)f2bf(h);
                u32 p01 = own | (((u32)__shfl_xor((int)own, 1)) << 16);
                if ((r & 1) == 0){
                    __hip_atomic_store(&hdst32[(size_t)m*(HH/2) + ((j0 + r) >> 1)], p01,
                                       __ATOMIC_RELAXED, __HIP_MEMORY_SCOPE_AGENT);
                }
            }

            asm volatile("s_waitcnt vmcnt(0)" ::: "memory");
            __syncthreads();
            if (tid == 0)
                __hip_atomic_store(&F0x[fidx], t + 2, __ATOMIC_RELAXED, __HIP_MEMORY_SCOPE_AGENT);

            if (t + 1 < TT){
                // ---- under-poll work: x(t+1) loads fly during the poll ----
                {
                    const u64* xrow = xb + ((size_t)(m0 + w*16 + r)*TT + (t+1))*(HH/4);
                    #pragma unroll
                    for (int kc = 0; kc < 16; kc++){
                        int jg0 = kc*8 + q*2;
                        xn[kc*2]   = __builtin_nontemporal_load(&xrow[jg0]);
                        xn[kc*2+1] = __builtin_nontemporal_load(&xrow[jg0+1]);
                    }
                }
                if (tid < 64){
                    if (lane < GRPB) poll_flag(&F0x[(mg*GRPB + lane)*FS], t + 2);         // peers
                    else             poll_flag(&F1x[(mg*GRPB + (lane-GRPB))*FS], t - 1);  // ring slack
                }
                __syncthreads();
                // issue hd(t) loads; pass A(t+1) covers their flight
                {
                    const u64* hrow = h0r + (size_t)(t & 3)*BB*(HH/4)
                                    + (size_t)(m0 + w*16 + r)*(HH/4);
                    #pragma unroll
                    for (int kc = 0; kc < 16; kc++){
                        int jg0 = kc*8 + q*2;
                        hd[kc*2]   = __hip_atomic_load(&hrow[jg0],   __ATOMIC_RELAXED, __HIP_MEMORY_SCOPE_AGENT);
                        hd[kc*2+1] = __hip_atomic_load(&hrow[jg0+1], __ATOMIC_RELAXED, __HIP_MEMORY_SCOPE_AGENT);
                    }
                }
                FENCE32(xn);
                for (int g = 0; g < 4; g++){
                    accA[g][0] = 0.f; accA[g][1] = 0.f; accA[g][2] = 0.f; accA[g][3] = 0.f;
                }
                #pragma unroll
                for (int kc = 0; kc < 16; kc++){
                    union { u64 d[2]; bf16x8 v; } au;
                    au.d[0] = xn[kc*2];
                    au.d[1] = xn[kc*2+1];
                    int cbase = kc*4 + q;
                    #pragma unroll
                    for (int g = 0; g < 4; g++){
                        int row = g*16 + r;
                        bf16x8 b = *(const bf16x8*)(&sWih[row*512 + ((cbase ^ (row & 7)) * 8)]);
                        accA[g] = __builtin_amdgcn_mfma_f32_16x16x32_bf16(au.v, b, accA[g], 0, 0, 0);
                    }
                }
            }
        }
    } else {
        // ======================= LAYER 1 =======================
        // wait h0(0) visible (L0 round 0 done)
        if (tid < GRPB)
            poll_flag(&F0x[(mg*GRPB + tid)*FS], 2);
        __syncthreads();

        for (int t = 0; t < TT; t++){
            const u64* xsrc = h0r + (size_t)(t & 3)*BB*(HH/4);   // h0(t), pre-relu
            const u64* hsrc = (t & 1) ? h1B : h1A;               // h1(t-1); t=0 -> zeros
            u64*       hdst = (t & 1) ? h1A : h1B;               // t=99 -> h1A
            const u64* xrow = xsrc + (size_t)(m0 + w*16 + r)*(HH/4);
            const u64* hrow = hsrc + (size_t)(m0 + w*16 + r)*(HH/4);

            // issue hx then hh back-to-back (one window); fence ONLY hx before
            // pass A so hh keeps flying under it
            u64 hx[32], hh[32];
            #pragma unroll
            for (int kc = 0; kc < 16; kc++){
                int jg0 = kc*8 + q*2;
                hx[kc*2]   = __hip_atomic_load(&xrow[jg0],   __ATOMIC_RELAXED, __HIP_MEMORY_SCOPE_AGENT);
                hx[kc*2+1] = __hip_atomic_load(&xrow[jg0+1], __ATOMIC_RELAXED, __HIP_MEMORY_SCOPE_AGENT);
            }
            #pragma unroll
            for (int kc = 0; kc < 16; kc++){
                int jg0 = kc*8 + q*2;
                hh[kc*2]   = __hip_atomic_load(&hrow[jg0],   __ATOMIC_RELAXED, __HIP_MEMORY_SCOPE_AGENT);
                hh[kc*2+1] = __hip_atomic_load(&hrow[jg0+1], __ATOMIC_RELAXED, __HIP_MEMORY_SCOPE_AGENT);
            }
            FENCE32(hx);
            // relu in-register (exact)
            #pragma unroll
            for (int i = 0; i < 32; i++) hx[i] = relu4_bf16(hx[i]);

            f32x4 acc[4];
            for (int g = 0; g < 4; g++){
                acc[g][0] = 0.f; acc[g][1] = 0.f; acc[g][2] = 0.f; acc[g][3] = 0.f;
            }
            // pass A: Wih1 @ relu(h0(t))   (hh loads in flight underneath)
            #pragma unroll
            for (int kc = 0; kc < 16; kc++){
                union { u64 d[2]; bf16x8 v; } au;
                au.d[0] = hx[kc*2];
                au.d[1] = hx[kc*2+1];
                int cbase = kc*4 + q;
                #pragma unroll
                for (int g = 0; g < 4; g++){
                    int row = g*16 + r;
                    bf16x8 b = *(const bf16x8*)(&sWih[row*512 + ((cbase ^ (row & 7)) * 8)]);
                    acc[g] = __builtin_amdgcn_mfma_f32_16x16x32_bf16(au.v, b, acc[g], 0, 0, 0);
                }
            }
            FENCE32(hh);
            // pass B: Whh1 @ h1(t-1)
            #pragma unroll
            for (int kc = 0; kc < 16; kc++){
                union { u64 d[2]; bf16x8 v; } au;
                au.d[0] = hh[kc*2];
                au.d[1] = hh[kc*2+1];
                int cbase = kc*4 + q;
                #pragma unroll
                for (int g = 0; g < 4; g++){
                    int row = g*16 + r;
                    bf16x8 b = *(const bf16x8*)(&sWhh[row*512 + ((cbase ^ (row & 7)) * 8)]);
                    acc[g] = __builtin_amdgcn_mfma_f32_16x16x32_bf16(au.v, b, acc[g], 0, 0, 0);
                }
            }

            u32* hdst32 = (u32*)hdst;
            #pragma unroll
            for (int reg = 0; reg < 4; reg++){
                int m = m0 + w*16 + q*4 + reg;
                float Gi = acc[0][reg] + bs[0];
                float Gf = acc[1][reg] + bs[1];
                float Gg = acc[2][reg] + bs[2];
                float Go = acc[3][reg] + bs[3];
                float iv = 1.f/(1.f + __expf(-Gi));
                float fv = 1.f/(1.f + __expf(-Gf));
                float gv = fast_tanh(Gg);
                float ov = 1.f/(1.f + __expf(-Go));
                float c = fv * creg[reg] + iv * gv;
                creg[reg] = c;
                float h = ov * fast_tanh(c);
                u32 own = (u32)f2bf(h);
                u32 p01 = own | (((u32)__shfl_xor((int)own, 1)) << 16);
                if ((r & 1) == 0){
                    __hip_atomic_store(&hdst32[(size_t)m*(HH/2) + ((j0 + r) >> 1)], p01,
                                       __ATOMIC_RELAXED, __HIP_MEMORY_SCOPE_AGENT);
                }
            }

            asm volatile("s_waitcnt vmcnt(0)" ::: "memory");
            __syncthreads();
            if (tid == 0)
                __hip_atomic_store(&F1x[fidx], t + 2, __ATOMIC_RELAXED, __HIP_MEMORY_SCOPE_AGENT);

            if (t + 1 < TT){
                if (tid < 64){
                    if (lane < GRPB) poll_flag(&F1x[(mg*GRPB + lane)*FS], t + 2);         // peers: h1(t)
                    else             poll_flag(&F0x[(mg*GRPB + (lane-GRPB))*FS], t + 3);  // h0(t+1)
                }
                __syncthreads();
            }
        }
    }
}

// ---- heads: fp32 output (d_out is float*), zero-sentinel kept ----
__global__ void k_heads(
    const u16* __restrict__ hfin, const float* __restrict__ Wout,
    const float* __restrict__ bout, const float* __restrict__ Wcls,
    const float* __restrict__ bcls, float* __restrict__ out)
{
    __shared__ float last[HH];
    int b = blockIdx.x, tid = threadIdx.x;
    for (int h = tid; h < HH; h += 256) last[h] = fmaxf(bf2f(hfin[b*HH + h]), 0.f);
    __syncthreads();
    for (int o = tid; o < NCONT + NCAT*VV; o += 256){
        if (o < NCONT){
            float a = bout[o];
            for (int h = 0; h < HH; h++) a += last[h] * Wout[h*NCONT + o];
            out[b*NCONT + o] = (a == 0.0f) ? 7.0f : a;
        } else {
            int oc = o - NCONT;
            int n = oc >> 5, v = oc & 31;
            float a = bcls[oc];
            const float* wp = Wcls + (size_t)n*HH*VV + v;
            for (int h = 0; h < HH; h++) a += last[h] * wp[h*VV];
            out[BB*NCONT + b*(NCAT*VV) + oc] = (a == 0.0f) ? 7.0f : a;
        }
    }
}

extern "C" void kernel_launch(void* const* d_in, const int* in_sizes, int n_in,
                              void* d_out, int out_size, void* d_ws, size_t ws_size,
                              hipStream_t stream){
    const float* x      = (const float*)d_in[0];
    const float* smean  = (const float*)d_in[1];
    const float* sscale = (const float*)d_in[2];
    const float* emb    = (const float*)d_in[3];
    const float* Win    = (const float*)d_in[4];
    const float* bin    = (const float*)d_in[5];
    const float* Wih    = (const float*)d_in[6];
    const float* Whh    = (const float*)d_in[7];
    const float* bih    = (const float*)d_in[8];
    const float* bhh    = (const float*)d_in[9];
    const float* Wout   = (const float*)d_in[10];
    const float* bout   = (const float*)d_in[11];
    const float* Wcls   = (const float*)d_in[12];
    const float* bcls   = (const float*)d_in[13];
    (void)in_sizes; (void)n_in; (void)out_size;

    char* ws = (char*)d_ws;
    size_t off = 0;
    u16*      feat  = (u16*)(ws + off);      off += (size_t)MTOT*KIN*2;   //   9.8 MB
    u16*      WinTb = (u16*)(ws + off);      off += (size_t)HH*KIN*2;     //   0.2 MB
    u16*      Xbuf  = (u16*)(ws + off);      off += (size_t)MTOT*HH*2;    //  26.2 MB
    u16*      Wihb  = (u16*)(ws + off);      off += (size_t)2*G4*HH*2;    //   4.2 MB
    u16*      Whhb  = (u16*)(ws + off);      off += (size_t)2*G4*HH*2;    //   4.2 MB
    u64*      h0r   = (u64*)(ws + off);      off += (size_t)4*BB*HH*2;    //   1.0 MB
    u64*      h1A   = (u64*)(ws + off);      off += (size_t)BB*HH*2;
    u64*      h1B   = (u64*)(ws + off);      off += (size_t)BB*HH*2;
    int*      bar   = (int*)(ws + off);      off += 4096*4;               //  16 KB
    (void)off; (void)ws_size;

    // fused weight prep: WinT + Wih cvt + Whh cvt in ONE dispatch
    int prep_n = HH*KIN + 2*2*G4*HH;
    PredictionModel_58841051955204_kernel<<<(prep_n + 255)/256, 256, 0, stream>>>(
        Win, WinTb, Wih, Wihb, Whh, Whhb);

    // featurize (+ bar zeroing in block 0)
    k_feat<<<1600, 256, 0, stream>>>(x, smean, sscale, emb, feat, bar);
    // Xbuf = relu(feat @ W_in + b_in) (bf16) — the only pre-GEMM left
    k_gemm<<<dim3(400, 2), 256, 0, stream>>>(feat, KIN, WinTb, KIN, bin, (const float*)0,
                                             Xbuf, HH, 6, 1, 0);
    // fused both-layer recurrence; L0 streams x from Xbuf
    k_rec2<<<256, 256, 131072, stream>>>(Wihb, Whhb, Xbuf, bih, bhh,
                                         h0r, h1A, h1B, bar);
    // T=100 even: layer-1 t=99 (odd) stores to h1A; heads write fp32 d_out
    k_heads<<<256, 256, 0, stream>>>((const u16*)h1A, Wout, bout, Wcls, bcls, (float*)d_out);
}